// Round 2
// baseline (4460.394 us; speedup 1.0000x reference)
//
#include <hip/hip_runtime.h>
#include <cstddef>
#include <cstdint>

// Transformer encoder fwd, MI355X. L=4, D=1024, H=16, DH=64, FF=4096, B=2, S=2048.
// Path A (ws >= 176MB): split-bf16 MFMA GEMMs (hi/lo decomposition, 3x
//   v_mfma_f32_32x32x16_bf16 per fp32 product) + fp32 flash attention.
// Path B (fallback): round-1 all-fp32 VALU implementation.

#define D_MODEL 1024
#define FF_DIM  4096
#define NTOK    4096
#define SEQ     2048
#define LLAYERS 4

using short8v = __attribute__((ext_vector_type(8))) short;   // 8 bf16 raw (4 VGPR)
using f32x16  = __attribute__((ext_vector_type(16))) float;  // 32x32 MFMA acc

#define FMA4(a_, s_, b_) { (a_).x += (s_)*(b_).x; (a_).y += (s_)*(b_).y; \
                           (a_).z += (s_)*(b_).z; (a_).w += (s_)*(b_).w; }

// ---------------------------------------------------------------- bf16 helpers
__device__ __forceinline__ unsigned short f2bf(float x) {
  unsigned int u = __float_as_uint(x);
  unsigned int r = u + 0x7fffu + ((u >> 16) & 1u);   // RNE; inputs finite
  return (unsigned short)(r >> 16);
}
__device__ __forceinline__ float bf2f(unsigned short h) {
  return __uint_as_float(((unsigned int)h) << 16);
}
__device__ __forceinline__ void split2(float x, short& hi, short& lo) {
  unsigned short h = f2bf(x);
  hi = (short)h;
  lo = (short)f2bf(x - bf2f(h));
}

// ---------------------------------------------------------------- LayerNorm
// One wave per row (D=1024 -> 16 floats/lane), 4 rows/block.
// HILO=0: fp32 out. HILO=1: bf16 hi/lo out (feeds MFMA GEMM).
template<int HILO>
__global__ __launch_bounds__(256)
void ln_k(const float* __restrict__ in, const float* __restrict__ w,
          const float* __restrict__ bia, float* __restrict__ outf,
          short* __restrict__ oh, short* __restrict__ ol)
{
  const int wv = threadIdx.x >> 6, lane = threadIdx.x & 63;
  const size_t row = (size_t)blockIdx.x * 4 + wv;
  const float4* x4 = reinterpret_cast<const float4*>(in + row * D_MODEL);
  float4 v[4];
  float s = 0.f;
#pragma unroll
  for (int i = 0; i < 4; i++) {
    v[i] = x4[lane + 64 * i];
    s += v[i].x + v[i].y + v[i].z + v[i].w;
  }
#pragma unroll
  for (int o = 32; o > 0; o >>= 1) s += __shfl_xor(s, o);
  const float mean = s * (1.f / D_MODEL);
  float qv = 0.f;
#pragma unroll
  for (int i = 0; i < 4; i++) {
    float a = v[i].x - mean, b = v[i].y - mean, c = v[i].z - mean, d = v[i].w - mean;
    qv += a * a + b * b + c * c + d * d;
  }
#pragma unroll
  for (int o = 32; o > 0; o >>= 1) qv += __shfl_xor(qv, o);
  const float rstd = rsqrtf(qv * (1.f / D_MODEL) + 1e-5f);
  const float4* w4 = reinterpret_cast<const float4*>(w);
  const float4* b4 = reinterpret_cast<const float4*>(bia);
#pragma unroll
  for (int i = 0; i < 4; i++) {
    float4 ww = w4[lane + 64 * i], bb = b4[lane + 64 * i], r;
    r.x = (v[i].x - mean) * rstd * ww.x + bb.x;
    r.y = (v[i].y - mean) * rstd * ww.y + bb.y;
    r.z = (v[i].z - mean) * rstd * ww.z + bb.z;
    r.w = (v[i].w - mean) * rstd * ww.w + bb.w;
    if (HILO) {
      short4 h, l;
      split2(r.x, h.x, l.x); split2(r.y, h.y, l.y);
      split2(r.z, h.z, l.z); split2(r.w, h.w, l.w);
      size_t off = row * D_MODEL + 4 * lane + 256 * i;
      *reinterpret_cast<short4*>(oh + off) = h;
      *reinterpret_cast<short4*>(ol + off) = l;
    } else {
      reinterpret_cast<float4*>(outf + row * D_MODEL)[lane + 64 * i] = r;
    }
  }
}

// ---------------------------------------------------------------- weight cvt
// Per-layer: W[K][N] fp32 -> W^T hi/lo bf16 [N][K], 32x32 LDS-tiled transpose.
struct WPack {
  const float* src[6];
  short* dhi[6];
  short* dlo[6];
  int K[6], N[6];
};
__global__ __launch_bounds__(256)
void cvtw_k(WPack p)
{
  __shared__ float t[32][36];
  const int b = blockIdx.x;
  int m, tile;
  if (b < 4096)      { m = b >> 10; tile = b & 1023; }       // Wq,Wk,Wv,Wo 1024x1024
  else if (b < 8192) { m = 4; tile = b - 4096; }             // W1 1024x4096
  else               { m = 5; tile = b - 8192; }             // W2 4096x1024
  const int K = p.K[m], N = p.N[m];
  const int sh = (m == 4) ? 7 : 5;                            // N/32 tiles per row
  const int k0 = (tile >> sh) * 32, n0 = (tile & ((1 << sh) - 1)) * 32;
  const int r = threadIdx.x >> 3, c4 = (threadIdx.x & 7) << 2;
  float4 v = *reinterpret_cast<const float4*>(p.src[m] + (size_t)(k0 + r) * N + n0 + c4);
  *reinterpret_cast<float4*>(&t[r][c4]) = v;
  __syncthreads();
  // thread (r, c4) writes T row (n0+r), ks k0+c4..+3
  short4 h, l;
  split2(t[c4 + 0][r], h.x, l.x);
  split2(t[c4 + 1][r], h.y, l.y);
  split2(t[c4 + 2][r], h.z, l.z);
  split2(t[c4 + 3][r], h.w, l.w);
  size_t off = (size_t)(n0 + r) * K + k0 + c4;
  *reinterpret_cast<short4*>(p.dhi[m] + off) = h;
  *reinterpret_cast<short4*>(p.dlo[m] + off) = l;
}

// ---------------------------------------------------------------- MFMA GEMM
// C[M,Ncols] = epi(A @ B + bias), A given as hi/lo bf16 [M][K], B given as
// B^T hi/lo bf16 [Ncols][K]. Split product: ah*bh + ah*bl + al*bh (fp32 acc).
// 128x128 tile, BK=64, 4 waves (2x2), wave tile 64x64 = 2x2 of 32x32 MFMAs.
// LDS tiles [128][64] bf16, XOR slot-swizzle (slot ^= row&7) for b128 frag reads.
// Fragment convention: A row = lane&31, B col = lane&31, shared k-order
// phi(g,j) = 8g+j (any shared bijection is correct: CDNA A/B k-maps are
// symmetric and HW pairs equal-k slots). C/D map HW-verified:
// col = lane&31, row = (reg&3) + 8*(reg>>2) + 4*(lane>>5).
// MODE 0: fp32 out = acc+bias (3-way split for fused QKV via nbn_per)
// MODE 1: fp32 out = acc+bias+resid
// MODE 2: hi/lo out = relu(acc+bias)
template<int MODE>
__global__ __launch_bounds__(256, 2)
void mgemm_k(const short* __restrict__ Ahg, const short* __restrict__ Alg,
             int K, int Ncols,
             const short* __restrict__ Wh0, const short* __restrict__ Wl0,
             const short* __restrict__ Wh1, const short* __restrict__ Wl1,
             const short* __restrict__ Wh2, const short* __restrict__ Wl2,
             const float* __restrict__ B0, const float* __restrict__ B1,
             const float* __restrict__ B2,
             float* __restrict__ O0, float* __restrict__ O1, float* __restrict__ O2,
             short* __restrict__ Oh, short* __restrict__ Ol,
             int nbn_per, const float* __restrict__ resid)
{
  __shared__ short Ash[2][128 * 64];   // [hi/lo][row*64 + swz-slot*8]
  __shared__ short Bsh[2][128 * 64];
  const int tid = threadIdx.x;
  const int split = blockIdx.x / nbn_per;
  const int bn = (blockIdx.x % nbn_per) * 128;
  const int bm = blockIdx.y * 128;
  const short* Wh = split == 0 ? Wh0 : (split == 1 ? Wh1 : Wh2);
  const short* Wl = split == 0 ? Wl0 : (split == 1 ? Wl1 : Wl2);
  const float* Bi = split == 0 ? B0 : (split == 1 ? B1 : B2);
  float* Of       = split == 0 ? O0 : (split == 1 ? O1 : O2);
  const int l = tid & 63, w = tid >> 6;
  const int wr = w >> 1, wc = w & 1;

  f32x16 acc[2][2];
#pragma unroll
  for (int a = 0; a < 2; a++)
#pragma unroll
    for (int b = 0; b < 2; b++)
#pragma unroll
      for (int i = 0; i < 16; i++) acc[a][b][i] = 0.f;

  // per-thread staging coords: 4 granules of 16B (8 bf16)
  int gr[4], gs[4], gdst[4];
#pragma unroll
  for (int c = 0; c < 4; c++) {
    int g = c * 256 + tid;
    gr[c] = g >> 3; gs[c] = g & 7;
    gdst[c] = gr[c] * 64 + ((gs[c] ^ (gr[c] & 7)) << 3);
  }

  for (int k0 = 0; k0 < K; k0 += 64) {
#pragma unroll
    for (int c = 0; c < 4; c++) {
      size_t ao = (size_t)(bm + gr[c]) * K + k0 + gs[c] * 8;
      size_t bo = (size_t)(bn + gr[c]) * K + k0 + gs[c] * 8;
      *reinterpret_cast<short8v*>(&Ash[0][gdst[c]]) = *reinterpret_cast<const short8v*>(Ahg + ao);
      *reinterpret_cast<short8v*>(&Ash[1][gdst[c]]) = *reinterpret_cast<const short8v*>(Alg + ao);
      *reinterpret_cast<short8v*>(&Bsh[0][gdst[c]]) = *reinterpret_cast<const short8v*>(Wh + bo);
      *reinterpret_cast<short8v*>(&Bsh[1][gdst[c]]) = *reinterpret_cast<const short8v*>(Wl + bo);
    }
    __syncthreads();
#pragma unroll
    for (int ks = 0; ks < 4; ks++) {
      const int slot = (ks << 1) | (l >> 5);
      short8v afh[2], afl[2], bfh[2], bfl[2];
#pragma unroll
      for (int rt = 0; rt < 2; rt++) {
        int row = wr * 64 + rt * 32 + (l & 31);
        int ia = row * 64 + ((slot ^ (row & 7)) << 3);
        afh[rt] = *reinterpret_cast<const short8v*>(&Ash[0][ia]);
        afl[rt] = *reinterpret_cast<const short8v*>(&Ash[1][ia]);
        int col = wc * 64 + rt * 32 + (l & 31);
        int ib = col * 64 + ((slot ^ (col & 7)) << 3);
        bfh[rt] = *reinterpret_cast<const short8v*>(&Bsh[0][ib]);
        bfl[rt] = *reinterpret_cast<const short8v*>(&Bsh[1][ib]);
      }
#pragma unroll
      for (int rt = 0; rt < 2; rt++)
#pragma unroll
        for (int ct = 0; ct < 2; ct++) {
          acc[rt][ct] = __builtin_amdgcn_mfma_f32_32x32x16_bf16(afh[rt], bfh[ct], acc[rt][ct], 0, 0, 0);
          acc[rt][ct] = __builtin_amdgcn_mfma_f32_32x32x16_bf16(afh[rt], bfl[ct], acc[rt][ct], 0, 0, 0);
          acc[rt][ct] = __builtin_amdgcn_mfma_f32_32x32x16_bf16(afl[rt], bfh[ct], acc[rt][ct], 0, 0, 0);
        }
    }
    __syncthreads();
  }

  const int rbase = (l >> 5) * 4, cl = l & 31;
#pragma unroll
  for (int rt = 0; rt < 2; rt++)
#pragma unroll
    for (int ct = 0; ct < 2; ct++) {
      const int colg = bn + wc * 64 + ct * 32 + cl;
      const float bia = Bi[colg];
#pragma unroll
      for (int reg = 0; reg < 16; reg++) {
        const int rowg = bm + wr * 64 + rt * 32 + rbase + (reg & 3) + ((reg >> 2) << 3);
        float v = acc[rt][ct][reg] + bia;
        const size_t off = (size_t)rowg * Ncols + colg;
        if (MODE == 1) v += resid[off];
        if (MODE == 2) {
          v = fmaxf(v, 0.f);
          short h, lo; split2(v, h, lo);
          Oh[off] = h; Ol[off] = lo;
        } else {
          Of[off] = v;
        }
      }
    }
}

// ---------------------------------------------------------------- fp32 GEMM (fallback)
template<bool RELU, bool RES>
__global__ __launch_bounds__(256)
void gemm_k(const float* __restrict__ A, int K, int Ncols,
            const float* __restrict__ W0, const float* __restrict__ W1p,
            const float* __restrict__ W2p,
            const float* __restrict__ B0, const float* __restrict__ B1p,
            const float* __restrict__ B2p,
            float* __restrict__ O0, float* __restrict__ O1p, float* __restrict__ O2p,
            int nbn_per, const float* __restrict__ resid)
{
  __shared__ float As[16][132];
  __shared__ float Bs[16][132];
  const int tid = threadIdx.x;
  const int split = blockIdx.x / nbn_per;
  const int bn = (blockIdx.x % nbn_per) * 128;
  const int bm = blockIdx.y * 128;
  const float* W  = split == 0 ? W0 : (split == 1 ? W1p : W2p);
  const float* Bi = split == 0 ? B0 : (split == 1 ? B1p : B2p);
  float* O        = split == 0 ? O0 : (split == 1 ? O1p : O2p);
  const int tx = tid & 15, ty = tid >> 4;

  float4 acc[2][4][2];
#pragma unroll
  for (int a = 0; a < 2; a++)
#pragma unroll
    for (int b = 0; b < 4; b++)
#pragma unroll
      for (int c = 0; c < 2; c++) acc[a][b][c] = make_float4(0.f, 0.f, 0.f, 0.f);

  for (int k0 = 0; k0 < K; k0 += 16) {
#pragma unroll
    for (int i = 0; i < 2; i++) {
      int p = tid + i * 256;
      int row = p >> 2, kk4 = (p & 3) << 2;
      float4 va = *reinterpret_cast<const float4*>(A + (size_t)(bm + row) * K + k0 + kk4);
      As[kk4 + 0][row] = va.x; As[kk4 + 1][row] = va.y;
      As[kk4 + 2][row] = va.z; As[kk4 + 3][row] = va.w;
    }
#pragma unroll
    for (int i = 0; i < 2; i++) {
      int p = tid + i * 256;
      int row = p >> 5, c4 = (p & 31) << 2;
      *reinterpret_cast<float4*>(&Bs[row][c4]) =
          *reinterpret_cast<const float4*>(W + (size_t)(k0 + row) * Ncols + bn + c4);
    }
    __syncthreads();
#pragma unroll
    for (int kk = 0; kk < 16; kk++) {
      float4 a0 = *reinterpret_cast<const float4*>(&As[kk][ty * 4]);
      float4 a1 = *reinterpret_cast<const float4*>(&As[kk][64 + ty * 4]);
      float4 b0 = *reinterpret_cast<const float4*>(&Bs[kk][tx * 4]);
      float4 b1 = *reinterpret_cast<const float4*>(&Bs[kk][64 + tx * 4]);
      float av0[4] = {a0.x, a0.y, a0.z, a0.w};
      float av1[4] = {a1.x, a1.y, a1.z, a1.w};
#pragma unroll
      for (int j = 0; j < 4; j++) {
        FMA4(acc[0][j][0], av0[j], b0); FMA4(acc[0][j][1], av0[j], b1);
        FMA4(acc[1][j][0], av1[j], b0); FMA4(acc[1][j][1], av1[j], b1);
      }
    }
    __syncthreads();
  }

#pragma unroll
  for (int ih = 0; ih < 2; ih++)
#pragma unroll
    for (int j = 0; j < 4; j++)
#pragma unroll
      for (int jh = 0; jh < 2; jh++) {
        int row = bm + ih * 64 + ty * 4 + j;
        int col = bn + jh * 64 + tx * 4;
        float4 r = acc[ih][j][jh];
        float4 bb = *reinterpret_cast<const float4*>(Bi + col);
        r.x += bb.x; r.y += bb.y; r.z += bb.z; r.w += bb.w;
        if (RES) {
          float4 rr = *reinterpret_cast<const float4*>(resid + (size_t)row * Ncols + col);
          r.x += rr.x; r.y += rr.y; r.z += rr.z; r.w += rr.w;
        }
        if (RELU) {
          r.x = fmaxf(r.x, 0.f); r.y = fmaxf(r.y, 0.f);
          r.z = fmaxf(r.z, 0.f); r.w = fmaxf(r.w, 0.f);
        }
        *reinterpret_cast<float4*>(O + (size_t)row * Ncols + col) = r;
      }
}

// ---------------------------------------------------------------- Flash attention (fp32)
// One block per (b, head, 128-row q-tile); online softmax; KT=64.
// HILO=1: epilogue writes bf16 hi/lo (feeds MFMA Wo GEMM).
template<int HILO>
__global__ __launch_bounds__(256)
void attn_k(const float* __restrict__ Q, const float* __restrict__ K,
            const float* __restrict__ V, float* __restrict__ Og,
            short* __restrict__ OhP, short* __restrict__ OlP)
{
  __shared__ float QsT[64][132];
  __shared__ float KsT[64][68];
  __shared__ float Vs[64][68];
  __shared__ float Ps[128][68];

  const int tid = threadIdx.x, tx = tid & 15, ty = tid >> 4;
  const int bh = blockIdx.y;
  const int bb = bh >> 4, hd = bh & 15;
  const int qt = blockIdx.x;
  const float* Qp = Q + (size_t)(bb * SEQ + qt * 128) * D_MODEL + hd * 64;
  const float* Kp = K + (size_t)(bb * SEQ) * D_MODEL + hd * 64;
  const float* Vp = V + (size_t)(bb * SEQ) * D_MODEL + hd * 64;
  const size_t obase = (size_t)(bb * SEQ + qt * 128) * D_MODEL + hd * 64;

#pragma unroll
  for (int i = 0; i < 8; i++) {
    int p = tid + i * 256;
    int r = p >> 4, k4 = (p & 15) << 2;
    float4 va = *reinterpret_cast<const float4*>(Qp + (size_t)r * D_MODEL + k4);
    QsT[k4 + 0][r] = va.x; QsT[k4 + 1][r] = va.y;
    QsT[k4 + 2][r] = va.z; QsT[k4 + 3][r] = va.w;
  }

  float4 Oa[2][4];
  float mrun[2][4], lrun[2][4];
#pragma unroll
  for (int a = 0; a < 2; a++)
#pragma unroll
    for (int j = 0; j < 4; j++) {
      Oa[a][j] = make_float4(0.f, 0.f, 0.f, 0.f);
      mrun[a][j] = -1e30f; lrun[a][j] = 0.f;
    }

  __syncthreads();

  for (int kt = 0; kt < 32; kt++) {
#pragma unroll
    for (int i = 0; i < 4; i++) {
      int p = tid + i * 256;
      int r = p >> 4, k4 = (p & 15) << 2;
      float4 kv = *reinterpret_cast<const float4*>(Kp + (size_t)(kt * 64 + r) * D_MODEL + k4);
      KsT[k4 + 0][r] = kv.x; KsT[k4 + 1][r] = kv.y;
      KsT[k4 + 2][r] = kv.z; KsT[k4 + 3][r] = kv.w;
      float4 vv = *reinterpret_cast<const float4*>(Vp + (size_t)(kt * 64 + r) * D_MODEL + k4);
      *reinterpret_cast<float4*>(&Vs[r][k4]) = vv;
    }
    __syncthreads();

    float4 sc[2][4];
#pragma unroll
    for (int a = 0; a < 2; a++)
#pragma unroll
      for (int j = 0; j < 4; j++) sc[a][j] = make_float4(0.f, 0.f, 0.f, 0.f);

#pragma unroll 8
    for (int kk = 0; kk < 64; kk++) {
      float4 b0 = *reinterpret_cast<const float4*>(&KsT[kk][tx * 4]);
      float4 a0 = *reinterpret_cast<const float4*>(&QsT[kk][ty * 4]);
      float4 a1 = *reinterpret_cast<const float4*>(&QsT[kk][64 + ty * 4]);
      float av0[4] = {a0.x, a0.y, a0.z, a0.w};
      float av1[4] = {a1.x, a1.y, a1.z, a1.w};
#pragma unroll
      for (int j = 0; j < 4; j++) {
        FMA4(sc[0][j], av0[j], b0);
        FMA4(sc[1][j], av1[j], b0);
      }
    }

#pragma unroll
    for (int a = 0; a < 2; a++)
#pragma unroll
      for (int j = 0; j < 4; j++) {
        float4 s4 = sc[a][j];
        s4.x *= 0.125f; s4.y *= 0.125f; s4.z *= 0.125f; s4.w *= 0.125f;
        float tm = fmaxf(fmaxf(s4.x, s4.y), fmaxf(s4.z, s4.w));
#pragma unroll
        for (int o = 8; o > 0; o >>= 1) tm = fmaxf(tm, __shfl_xor(tm, o));
        float mnew = fmaxf(mrun[a][j], tm);
        float alpha = __expf(mrun[a][j] - mnew);
        float4 p;
        p.x = __expf(s4.x - mnew); p.y = __expf(s4.y - mnew);
        p.z = __expf(s4.z - mnew); p.w = __expf(s4.w - mnew);
        float ps = p.x + p.y + p.z + p.w;
#pragma unroll
        for (int o = 8; o > 0; o >>= 1) ps += __shfl_xor(ps, o);
        lrun[a][j] = lrun[a][j] * alpha + ps;
        mrun[a][j] = mnew;
        Oa[a][j].x *= alpha; Oa[a][j].y *= alpha;
        Oa[a][j].z *= alpha; Oa[a][j].w *= alpha;
        *reinterpret_cast<float4*>(&Ps[a * 64 + ty * 4 + j][tx * 4]) = p;
      }
    __syncthreads();

#pragma unroll 4
    for (int k4 = 0; k4 < 16; k4++) {
      float4 b[4];
#pragma unroll
      for (int u = 0; u < 4; u++)
        b[u] = *reinterpret_cast<const float4*>(&Vs[k4 * 4 + u][tx * 4]);
#pragma unroll
      for (int a = 0; a < 2; a++)
#pragma unroll
        for (int j = 0; j < 4; j++) {
          float4 p = *reinterpret_cast<const float4*>(&Ps[a * 64 + ty * 4 + j][k4 * 4]);
          FMA4(Oa[a][j], p.x, b[0]);
          FMA4(Oa[a][j], p.y, b[1]);
          FMA4(Oa[a][j], p.z, b[2]);
          FMA4(Oa[a][j], p.w, b[3]);
        }
    }
    __syncthreads();
  }

#pragma unroll
  for (int a = 0; a < 2; a++)
#pragma unroll
    for (int j = 0; j < 4; j++) {
      float inv = 1.f / lrun[a][j];
      float4 r = Oa[a][j];
      r.x *= inv; r.y *= inv; r.z *= inv; r.w *= inv;
      size_t off = obase + (size_t)(a * 64 + ty * 4 + j) * D_MODEL + tx * 4;
      if (HILO) {
        short4 h, lo;
        split2(r.x, h.x, lo.x); split2(r.y, h.y, lo.y);
        split2(r.z, h.z, lo.z); split2(r.w, h.w, lo.w);
        *reinterpret_cast<short4*>(OhP + off) = h;
        *reinterpret_cast<short4*>(OlP + off) = lo;
      } else {
        *reinterpret_cast<float4*>(Og + off) = r;
      }
    }
}

// ---------------------------------------------------------------- launch
extern "C" void kernel_launch(void* const* d_in, const int* in_sizes, int n_in,
                              void* d_out, int out_size, void* d_ws, size_t ws_size,
                              hipStream_t stream)
{
  (void)in_sizes; (void)n_in; (void)out_size;
  const float* x    = (const float*)d_in[0];
  const float* Wq   = (const float*)d_in[1];
  const float* Wk   = (const float*)d_in[2];
  const float* Wv   = (const float*)d_in[3];
  const float* Wo   = (const float*)d_in[4];
  const float* bq   = (const float*)d_in[5];
  const float* bk   = (const float*)d_in[6];
  const float* bv   = (const float*)d_in[7];
  const float* bo   = (const float*)d_in[8];
  const float* W1   = (const float*)d_in[9];
  const float* b1   = (const float*)d_in[10];
  const float* W2   = (const float*)d_in[11];
  const float* b2   = (const float*)d_in[12];
  const float* ln1w = (const float*)d_in[13];
  const float* ln1b = (const float*)d_in[14];
  const float* ln2w = (const float*)d_in[15];
  const float* ln2b = (const float*)d_in[16];
  const float* lnfw = (const float*)d_in[17];
  const float* lnfb = (const float*)d_in[18];

  const size_t ND = (size_t)NTOK * D_MODEL;     // 4M
  const size_t M1 = 1024 * 1024;
  float* xb = (float*)d_out;                    // residual stream in d_out

  hipMemcpyAsync(xb, x, sizeof(float) * ND, hipMemcpyDeviceToDevice, stream);

  // MFMA path workspace: wT hi/lo (24MB x2) | h hi/lo (8MB x2) | q,k,v fp32
  // (16MB x3) | t hi/lo (32MB x2) = 176MB total.
  const size_t REQ_MFMA = 184549376;
  const bool use_mfma = (ws_size >= REQ_MFMA);

  if (use_mfma) {
    short* wT_h = (short*)d_ws;                 // per-layer: qT,kT,vT,oT @0/1M/2M/3M; W1T @4M; W2T @8M
    short* wT_l = wT_h + 12 * M1;
    short* h_hi = wT_l + 12 * M1;
    short* h_lo = h_hi + ND;
    float* qb   = (float*)(h_lo + ND);
    float* kb   = qb + ND;
    float* vb   = kb + ND;
    short* t_hi = (short*)(vb + ND);
    short* t_lo = t_hi + (size_t)NTOK * FF_DIM;

    for (int i = 0; i < LLAYERS; i++) {
      WPack p;
      p.src[0] = Wq + (size_t)i * M1; p.src[1] = Wk + (size_t)i * M1;
      p.src[2] = Wv + (size_t)i * M1; p.src[3] = Wo + (size_t)i * M1;
      p.src[4] = W1 + (size_t)i * D_MODEL * FF_DIM;
      p.src[5] = W2 + (size_t)i * FF_DIM * D_MODEL;
      for (int m = 0; m < 6; m++) {
        static const size_t doff[6] = {0, M1, 2 * M1, 3 * M1, 4 * M1, 8 * M1};
        p.dhi[m] = wT_h + doff[m]; p.dlo[m] = wT_l + doff[m];
      }
      p.K[0] = p.K[1] = p.K[2] = p.K[3] = 1024; p.K[4] = 1024; p.K[5] = 4096;
      p.N[0] = p.N[1] = p.N[2] = p.N[3] = 1024; p.N[4] = 4096; p.N[5] = 1024;
      cvtw_k<<<12288, 256, 0, stream>>>(p);

      ln_k<1><<<NTOK / 4, 256, 0, stream>>>(xb, ln1w + (size_t)i * D_MODEL,
                                            ln1b + (size_t)i * D_MODEL, nullptr, h_hi, h_lo);
      // fused QKV (split 0/1/2 over blockIdx.x / 8)
      mgemm_k<0><<<dim3(24, 32), 256, 0, stream>>>(
          h_hi, h_lo, 1024, 1024,
          wT_h, wT_l, wT_h + M1, wT_l + M1, wT_h + 2 * M1, wT_l + 2 * M1,
          bq + (size_t)i * D_MODEL, bk + (size_t)i * D_MODEL, bv + (size_t)i * D_MODEL,
          qb, kb, vb, nullptr, nullptr, 8, nullptr);
      attn_k<1><<<dim3(16, 32), 256, 0, stream>>>(qb, kb, vb, nullptr, h_hi, h_lo);
      // x += attn @ Wo + bo
      mgemm_k<1><<<dim3(8, 32), 256, 0, stream>>>(
          h_hi, h_lo, 1024, 1024,
          wT_h + 3 * M1, wT_l + 3 * M1, wT_h + 3 * M1, wT_l + 3 * M1, wT_h + 3 * M1, wT_l + 3 * M1,
          bo + (size_t)i * D_MODEL, bo + (size_t)i * D_MODEL, bo + (size_t)i * D_MODEL,
          xb, xb, xb, nullptr, nullptr, 8, xb);
      ln_k<1><<<NTOK / 4, 256, 0, stream>>>(xb, ln2w + (size_t)i * D_MODEL,
                                            ln2b + (size_t)i * D_MODEL, nullptr, h_hi, h_lo);
      // t = relu(h @ W1 + b1) -> hi/lo
      mgemm_k<2><<<dim3(32, 32), 256, 0, stream>>>(
          h_hi, h_lo, 1024, 4096,
          wT_h + 4 * M1, wT_l + 4 * M1, wT_h + 4 * M1, wT_l + 4 * M1, wT_h + 4 * M1, wT_l + 4 * M1,
          b1 + (size_t)i * FF_DIM, b1 + (size_t)i * FF_DIM, b1 + (size_t)i * FF_DIM,
          nullptr, nullptr, nullptr, t_hi, t_lo, 32, nullptr);
      // x += t @ W2 + b2
      mgemm_k<1><<<dim3(8, 32), 256, 0, stream>>>(
          t_hi, t_lo, 4096, 1024,
          wT_h + 8 * M1, wT_l + 8 * M1, wT_h + 8 * M1, wT_l + 8 * M1, wT_h + 8 * M1, wT_l + 8 * M1,
          b2 + (size_t)i * D_MODEL, b2 + (size_t)i * D_MODEL, b2 + (size_t)i * D_MODEL,
          xb, xb, xb, nullptr, nullptr, 8, xb);
    }
    ln_k<0><<<NTOK / 4, 256, 0, stream>>>(xb, lnfw, lnfb, xb, nullptr, nullptr);
    return;
  }

  // ---------------- fallback: round-1 fp32 VALU path (needs 80MB ws) ----------------
  float* h  = (float*)d_ws;
  float* qb = h + ND;
  float* kb = qb + ND;
  float* vb = kb + ND;
  float* tb = qb;                               // FFN act aliases q/k/v

  for (int i = 0; i < LLAYERS; i++) {
    const float* Wq_l = Wq + (size_t)i * M1;
    const float* Wk_l = Wk + (size_t)i * M1;
    const float* Wv_l = Wv + (size_t)i * M1;
    const float* Wo_l = Wo + (size_t)i * M1;
    const float* W1_l = W1 + (size_t)i * D_MODEL * FF_DIM;
    const float* W2_l = W2 + (size_t)i * FF_DIM * D_MODEL;

    ln_k<0><<<NTOK / 4, 256, 0, stream>>>(xb, ln1w + (size_t)i * D_MODEL,
                                          ln1b + (size_t)i * D_MODEL, h, nullptr, nullptr);
    gemm_k<false, false><<<dim3(24, 32), 256, 0, stream>>>(
        h, D_MODEL, D_MODEL, Wq_l, Wk_l, Wv_l,
        bq + (size_t)i * D_MODEL, bk + (size_t)i * D_MODEL, bv + (size_t)i * D_MODEL,
        qb, kb, vb, 8, nullptr);
    attn_k<0><<<dim3(16, 32), 256, 0, stream>>>(qb, kb, vb, h, nullptr, nullptr);
    gemm_k<false, true><<<dim3(8, 32), 256, 0, stream>>>(
        h, D_MODEL, D_MODEL, Wo_l, Wo_l, Wo_l,
        bo + (size_t)i * D_MODEL, bo + (size_t)i * D_MODEL, bo + (size_t)i * D_MODEL,
        xb, xb, xb, 8, xb);
    ln_k<0><<<NTOK / 4, 256, 0, stream>>>(xb, ln2w + (size_t)i * D_MODEL,
                                          ln2b + (size_t)i * D_MODEL, h, nullptr, nullptr);
    gemm_k<true, false><<<dim3(32, 32), 256, 0, stream>>>(
        h, D_MODEL, FF_DIM, W1_l, W1_l, W1_l,
        b1 + (size_t)i * FF_DIM, b1 + (size_t)i * FF_DIM, b1 + (size_t)i * FF_DIM,
        tb, tb, tb, 32, nullptr);
    gemm_k<false, true><<<dim3(8, 32), 256, 0, stream>>>(
        tb, FF_DIM, D_MODEL, W2_l, W2_l, W2_l,
        b2 + (size_t)i * D_MODEL, b2 + (size_t)i * D_MODEL, b2 + (size_t)i * D_MODEL,
        xb, xb, xb, 8, xb);
  }
  ln_k<0><<<NTOK / 4, 256, 0, stream>>>(xb, lnfw, lnfb, xb, nullptr, nullptr);
}

// Round 3
// 2403.446 us; speedup vs baseline: 1.8558x; 1.8558x over previous
//
#include <hip/hip_runtime.h>
#include <cstddef>
#include <cstdint>

// Transformer encoder fwd, MI355X. L=4, D=1024, H=16, DH=64, FF=4096, B=2, S=2048.
// Path A (ws >= 176MB): split-bf16 MFMA GEMMs + split-bf16 MFMA flash attention
//   (swapped QK^T: S^T = mfma(K,Q) -> in-lane softmax; PV via reg-packed P^T
//   fragments against a phi-permuted global V^T layout).
// Path B (fallback): all-fp32 VALU implementation.

#define D_MODEL 1024
#define FF_DIM  4096
#define NTOK    4096
#define SEQ     2048
#define LLAYERS 4

using short8v = __attribute__((ext_vector_type(8))) short;   // 8 bf16 raw (4 VGPR)
using f32x16  = __attribute__((ext_vector_type(16))) float;  // 32x32 MFMA acc

#define FMA4(a_, s_, b_) { (a_).x += (s_)*(b_).x; (a_).y += (s_)*(b_).y; \
                           (a_).z += (s_)*(b_).z; (a_).w += (s_)*(b_).w; }

// ---------------------------------------------------------------- bf16 helpers
__device__ __forceinline__ unsigned short f2bf(float x) {
  unsigned int u = __float_as_uint(x);
  unsigned int r = u + 0x7fffu + ((u >> 16) & 1u);   // RNE; inputs finite
  return (unsigned short)(r >> 16);
}
__device__ __forceinline__ float bf2f(unsigned short h) {
  return __uint_as_float(((unsigned int)h) << 16);
}
__device__ __forceinline__ void split2(float x, short& hi, short& lo) {
  unsigned short h = f2bf(x);
  hi = (short)h;
  lo = (short)f2bf(x - bf2f(h));
}

// ---------------------------------------------------------------- LayerNorm
template<int HILO>
__global__ __launch_bounds__(256)
void ln_k(const float* __restrict__ in, const float* __restrict__ w,
          const float* __restrict__ bia, float* __restrict__ outf,
          short* __restrict__ oh, short* __restrict__ ol)
{
  const int wv = threadIdx.x >> 6, lane = threadIdx.x & 63;
  const size_t row = (size_t)blockIdx.x * 4 + wv;
  const float4* x4 = reinterpret_cast<const float4*>(in + row * D_MODEL);
  float4 v[4];
  float s = 0.f;
#pragma unroll
  for (int i = 0; i < 4; i++) {
    v[i] = x4[lane + 64 * i];
    s += v[i].x + v[i].y + v[i].z + v[i].w;
  }
#pragma unroll
  for (int o = 32; o > 0; o >>= 1) s += __shfl_xor(s, o);
  const float mean = s * (1.f / D_MODEL);
  float qv = 0.f;
#pragma unroll
  for (int i = 0; i < 4; i++) {
    float a = v[i].x - mean, b = v[i].y - mean, c = v[i].z - mean, d = v[i].w - mean;
    qv += a * a + b * b + c * c + d * d;
  }
#pragma unroll
  for (int o = 32; o > 0; o >>= 1) qv += __shfl_xor(qv, o);
  const float rstd = rsqrtf(qv * (1.f / D_MODEL) + 1e-5f);
  const float4* w4 = reinterpret_cast<const float4*>(w);
  const float4* b4 = reinterpret_cast<const float4*>(bia);
#pragma unroll
  for (int i = 0; i < 4; i++) {
    float4 ww = w4[lane + 64 * i], bb = b4[lane + 64 * i], r;
    r.x = (v[i].x - mean) * rstd * ww.x + bb.x;
    r.y = (v[i].y - mean) * rstd * ww.y + bb.y;
    r.z = (v[i].z - mean) * rstd * ww.z + bb.z;
    r.w = (v[i].w - mean) * rstd * ww.w + bb.w;
    if (HILO) {
      short4 h, l;
      split2(r.x, h.x, l.x); split2(r.y, h.y, l.y);
      split2(r.z, h.z, l.z); split2(r.w, h.w, l.w);
      size_t off = row * D_MODEL + 4 * lane + 256 * i;
      *reinterpret_cast<short4*>(oh + off) = h;
      *reinterpret_cast<short4*>(ol + off) = l;
    } else {
      reinterpret_cast<float4*>(outf + row * D_MODEL)[lane + 64 * i] = r;
    }
  }
}

// ---------------------------------------------------------------- weight cvt
struct WPack {
  const float* src[6];
  short* dhi[6];
  short* dlo[6];
  int K[6], N[6];
};
__global__ __launch_bounds__(256)
void cvtw_k(WPack p)
{
  __shared__ float t[32][36];
  const int b = blockIdx.x;
  int m, tile;
  if (b < 4096)      { m = b >> 10; tile = b & 1023; }
  else if (b < 8192) { m = 4; tile = b - 4096; }
  else               { m = 5; tile = b - 8192; }
  const int K = p.K[m], N = p.N[m];
  const int sh = (m == 4) ? 7 : 5;
  const int k0 = (tile >> sh) * 32, n0 = (tile & ((1 << sh) - 1)) * 32;
  const int r = threadIdx.x >> 3, c4 = (threadIdx.x & 7) << 2;
  float4 v = *reinterpret_cast<const float4*>(p.src[m] + (size_t)(k0 + r) * N + n0 + c4);
  *reinterpret_cast<float4*>(&t[r][c4]) = v;
  __syncthreads();
  short4 h, l;
  split2(t[c4 + 0][r], h.x, l.x);
  split2(t[c4 + 1][r], h.y, l.y);
  split2(t[c4 + 2][r], h.z, l.z);
  split2(t[c4 + 3][r], h.w, l.w);
  size_t off = (size_t)(n0 + r) * K + k0 + c4;
  *reinterpret_cast<short4*>(p.dhi[m] + off) = h;
  *reinterpret_cast<short4*>(p.dlo[m] + off) = l;
}

// ---------------------------------------------------------------- MFMA GEMM
// MODE 0: fp32 out = acc+bias
// MODE 1: fp32 out = acc+bias+resid
// MODE 2: hi/lo out (OhA/OlA) = relu(acc+bias)
// MODE 3: QKV: split 0/1 -> row-major hi/lo (A/B pairs); split 2 -> V^T
//         phi-permuted scatter (C pair), layout [b*16+h][64 d][2048 rho(s)]
template<int MODE>
__global__ __launch_bounds__(256, 2)
void mgemm_k(const short* __restrict__ Ahg, const short* __restrict__ Alg,
             int K, int Ncols,
             const short* __restrict__ Wh0, const short* __restrict__ Wl0,
             const short* __restrict__ Wh1, const short* __restrict__ Wl1,
             const short* __restrict__ Wh2, const short* __restrict__ Wl2,
             const float* __restrict__ B0, const float* __restrict__ B1,
             const float* __restrict__ B2,
             float* __restrict__ O0, float* __restrict__ O1, float* __restrict__ O2,
             short* __restrict__ OhA, short* __restrict__ OlA,
             short* __restrict__ OhB, short* __restrict__ OlB,
             short* __restrict__ OhC, short* __restrict__ OlC,
             int nbn_per, const float* __restrict__ resid)
{
  __shared__ short Ash[2][128 * 64];
  __shared__ short Bsh[2][128 * 64];
  const int tid = threadIdx.x;
  const int split = blockIdx.x / nbn_per;
  const int bn = (blockIdx.x % nbn_per) * 128;
  const int bm = blockIdx.y * 128;
  const short* Wh = split == 0 ? Wh0 : (split == 1 ? Wh1 : Wh2);
  const short* Wl = split == 0 ? Wl0 : (split == 1 ? Wl1 : Wl2);
  const float* Bi = split == 0 ? B0 : (split == 1 ? B1 : B2);
  float* Of       = split == 0 ? O0 : (split == 1 ? O1 : O2);
  const int l = tid & 63, w = tid >> 6;
  const int wr = w >> 1, wc = w & 1;

  f32x16 acc[2][2];
#pragma unroll
  for (int a = 0; a < 2; a++)
#pragma unroll
    for (int b = 0; b < 2; b++)
#pragma unroll
      for (int i = 0; i < 16; i++) acc[a][b][i] = 0.f;

  int gr[4], gs[4], gdst[4];
#pragma unroll
  for (int c = 0; c < 4; c++) {
    int g = c * 256 + tid;
    gr[c] = g >> 3; gs[c] = g & 7;
    gdst[c] = gr[c] * 64 + ((gs[c] ^ (gr[c] & 7)) << 3);
  }

  for (int k0 = 0; k0 < K; k0 += 64) {
#pragma unroll
    for (int c = 0; c < 4; c++) {
      size_t ao = (size_t)(bm + gr[c]) * K + k0 + gs[c] * 8;
      size_t bo = (size_t)(bn + gr[c]) * K + k0 + gs[c] * 8;
      *reinterpret_cast<short8v*>(&Ash[0][gdst[c]]) = *reinterpret_cast<const short8v*>(Ahg + ao);
      *reinterpret_cast<short8v*>(&Ash[1][gdst[c]]) = *reinterpret_cast<const short8v*>(Alg + ao);
      *reinterpret_cast<short8v*>(&Bsh[0][gdst[c]]) = *reinterpret_cast<const short8v*>(Wh + bo);
      *reinterpret_cast<short8v*>(&Bsh[1][gdst[c]]) = *reinterpret_cast<const short8v*>(Wl + bo);
    }
    __syncthreads();
#pragma unroll
    for (int ks = 0; ks < 4; ks++) {
      const int slot = (ks << 1) | (l >> 5);
      short8v afh[2], afl[2], bfh[2], bfl[2];
#pragma unroll
      for (int rt = 0; rt < 2; rt++) {
        int row = wr * 64 + rt * 32 + (l & 31);
        int ia = row * 64 + ((slot ^ (row & 7)) << 3);
        afh[rt] = *reinterpret_cast<const short8v*>(&Ash[0][ia]);
        afl[rt] = *reinterpret_cast<const short8v*>(&Ash[1][ia]);
        int col = wc * 64 + rt * 32 + (l & 31);
        int ib = col * 64 + ((slot ^ (col & 7)) << 3);
        bfh[rt] = *reinterpret_cast<const short8v*>(&Bsh[0][ib]);
        bfl[rt] = *reinterpret_cast<const short8v*>(&Bsh[1][ib]);
      }
#pragma unroll
      for (int rt = 0; rt < 2; rt++)
#pragma unroll
        for (int ct = 0; ct < 2; ct++) {
          acc[rt][ct] = __builtin_amdgcn_mfma_f32_32x32x16_bf16(afh[rt], bfh[ct], acc[rt][ct], 0, 0, 0);
          acc[rt][ct] = __builtin_amdgcn_mfma_f32_32x32x16_bf16(afh[rt], bfl[ct], acc[rt][ct], 0, 0, 0);
          acc[rt][ct] = __builtin_amdgcn_mfma_f32_32x32x16_bf16(afl[rt], bfh[ct], acc[rt][ct], 0, 0, 0);
        }
    }
    __syncthreads();
  }

  const int rbase = (l >> 5) * 4, cl = l & 31;
#pragma unroll
  for (int rt = 0; rt < 2; rt++)
#pragma unroll
    for (int ct = 0; ct < 2; ct++) {
      const int colg = bn + wc * 64 + ct * 32 + cl;
      const float bia = Bi[colg];
#pragma unroll
      for (int reg = 0; reg < 16; reg++) {
        const int rowg = bm + wr * 64 + rt * 32 + rbase + (reg & 3) + ((reg >> 2) << 3);
        float v = acc[rt][ct][reg] + bia;
        const size_t off = (size_t)rowg * Ncols + colg;
        if (MODE == 0) {
          Of[off] = v;
        } else if (MODE == 1) {
          Of[off] = v + resid[off];
        } else if (MODE == 2) {
          v = fmaxf(v, 0.f);
          short h, lo; split2(v, h, lo);
          OhA[off] = h; OlA[off] = lo;
        } else {  // MODE 3
          short h, lo; split2(v, h, lo);
          if (split < 2) {
            short* OH = split == 0 ? OhA : OhB;
            short* OL = split == 0 ? OlA : OlB;
            OH[off] = h; OL[off] = lo;
          } else {
            const int bbv = rowg >> 11, s = rowg & 2047;
            const int hdv = colg >> 6, dv = colg & 63;
            const int m = s & 15;
            const int pos = (m & 3) + ((m >> 3) << 2) + (((m >> 2) & 1) << 3);
            const size_t voff = ((size_t)(bbv * 16 + hdv) * 64 + dv) * SEQ + (s - m + pos);
            OhC[voff] = h; OlC[voff] = lo;
          }
        }
      }
    }
}

// ---------------------------------------------------------------- MFMA flash attention
// Block = (qtile of 128, b*16+h). 4 waves, each owns 32 q rows.
// S^T = mfma(A=K, B=Q): lane (q=l&31, hb=l>>5) holds S[q][kv], kv = 32t+(r&3)+8(r>>2)+4hb.
// P packed in-reg as B-frags with k-order phi(h,j)=(j&3)+8(j>>2)+4h;
// V^T pre-permuted globally (rho) so A-frags are contiguous b128 from swizzled LDS.
// O^T accum; epilogue scatters O[q][d] as hi/lo bf16.
__global__ __launch_bounds__(256)
void mattn_k(const short* __restrict__ qh, const short* __restrict__ ql,
             const short* __restrict__ kh, const short* __restrict__ kl,
             const short* __restrict__ vth, const short* __restrict__ vtl,
             short* __restrict__ oh, short* __restrict__ ol)
{
  __shared__ short Kh[64 * 64], Kl[64 * 64], Vh[64 * 64], Vl[64 * 64];  // 32 KB
  const int tid = threadIdx.x;
  const int l = tid & 63, wv = tid >> 6;
  const int lq = l & 31, hb = l >> 5;
  const int qt = blockIdx.x, bh = blockIdx.y;
  const int bb = bh >> 4, hd = bh & 15;

  // Q fragments: this wave's 32 q rows, 4 dh-chunks, hi/lo
  const size_t qoff = (size_t)(bb * SEQ + qt * 128 + wv * 32 + lq) * D_MODEL + hd * 64 + 8 * hb;
  short8v qfh[4], qfl[4];
#pragma unroll
  for (int c = 0; c < 4; c++) {
    qfh[c] = *reinterpret_cast<const short8v*>(qh + qoff + 16 * c);
    qfl[c] = *reinterpret_cast<const short8v*>(ql + qoff + 16 * c);
  }

  // staging: 2 granules (16B) per thread per array
  int dst[2];
  size_t kga[2], vga[2];
#pragma unroll
  for (int c = 0; c < 2; c++) {
    int g = tid + c * 256;
    int rr = g >> 3, ss = g & 7;
    dst[c] = rr * 64 + ((ss ^ (rr & 7)) << 3);
    kga[c] = (size_t)(bb * SEQ + rr) * D_MODEL + hd * 64 + ss * 8;
    vga[c] = (size_t)(bh * 64 + rr) * SEQ + ss * 8;
  }
  short8v skh[2], skl[2], svh[2], svl[2];
#pragma unroll
  for (int c = 0; c < 2; c++) {
    skh[c] = *reinterpret_cast<const short8v*>(kh + kga[c]);
    skl[c] = *reinterpret_cast<const short8v*>(kl + kga[c]);
    svh[c] = *reinterpret_cast<const short8v*>(vth + vga[c]);
    svl[c] = *reinterpret_cast<const short8v*>(vtl + vga[c]);
  }

  f32x16 accO[2];
#pragma unroll
  for (int t = 0; t < 2; t++)
#pragma unroll
    for (int i = 0; i < 16; i++) accO[t][i] = 0.f;
  float mrun = -3e38f, lrun = 0.f;

  for (int kt = 0; kt < 32; kt++) {
#pragma unroll
    for (int c = 0; c < 2; c++) {
      *reinterpret_cast<short8v*>(&Kh[dst[c]]) = skh[c];
      *reinterpret_cast<short8v*>(&Kl[dst[c]]) = skl[c];
      *reinterpret_cast<short8v*>(&Vh[dst[c]]) = svh[c];
      *reinterpret_cast<short8v*>(&Vl[dst[c]]) = svl[c];
    }
    __syncthreads();
    if (kt < 31) {                       // T14: issue next tile's loads early
#pragma unroll
      for (int c = 0; c < 2; c++) {
        size_t ko = kga[c] + (size_t)(kt + 1) * 64 * D_MODEL;
        size_t vo = vga[c] + (size_t)(kt + 1) * 64;
        skh[c] = *reinterpret_cast<const short8v*>(kh + ko);
        skl[c] = *reinterpret_cast<const short8v*>(kl + ko);
        svh[c] = *reinterpret_cast<const short8v*>(vth + vo);
        svl[c] = *reinterpret_cast<const short8v*>(vtl + vo);
      }
    }

    // ---- S^T = K * Q^T (split bf16, 24 MFMAs)
    f32x16 sc[2];
#pragma unroll
    for (int t = 0; t < 2; t++)
#pragma unroll
      for (int i = 0; i < 16; i++) sc[t][i] = 0.f;
    __builtin_amdgcn_s_setprio(1);
#pragma unroll
    for (int t = 0; t < 2; t++) {
      const int row = 32 * t + lq;
#pragma unroll
      for (int c = 0; c < 4; c++) {
        const int idx = row * 64 + (((2 * c + hb) ^ (row & 7)) << 3);
        short8v ah = *reinterpret_cast<const short8v*>(&Kh[idx]);
        short8v al = *reinterpret_cast<const short8v*>(&Kl[idx]);
        sc[t] = __builtin_amdgcn_mfma_f32_32x32x16_bf16(ah, qfh[c], sc[t], 0, 0, 0);
        sc[t] = __builtin_amdgcn_mfma_f32_32x32x16_bf16(ah, qfl[c], sc[t], 0, 0, 0);
        sc[t] = __builtin_amdgcn_mfma_f32_32x32x16_bf16(al, qfh[c], sc[t], 0, 0, 0);
      }
    }
    __builtin_amdgcn_s_setprio(0);

    // ---- online softmax (in-lane 32 values + cross-half shfl)
    float p[2][16];
    float tm = -3e38f;
#pragma unroll
    for (int t = 0; t < 2; t++)
#pragma unroll
      for (int r = 0; r < 16; r++) {
        p[t][r] = sc[t][r] * 0.125f;
        tm = fmaxf(tm, p[t][r]);
      }
    tm = fmaxf(tm, __shfl_xor(tm, 32));
    const float mnew = fmaxf(mrun, tm);
    const float alpha = __expf(mrun - mnew);
    float ps = 0.f;
#pragma unroll
    for (int t = 0; t < 2; t++)
#pragma unroll
      for (int r = 0; r < 16; r++) {
        p[t][r] = __expf(p[t][r] - mnew);
        ps += p[t][r];
      }
    ps += __shfl_xor(ps, 32);
    lrun = lrun * alpha + ps;
    mrun = mnew;
#pragma unroll
    for (int t = 0; t < 2; t++)
#pragma unroll
      for (int i = 0; i < 16; i++) accO[t][i] *= alpha;

    // ---- pack P hi/lo B-frags: chunk c <- p[c>>1][8*(c&1)+j]
    short8v ph[4], pl[4];
#pragma unroll
    for (int c = 0; c < 4; c++) {
#pragma unroll
      for (int j = 0; j < 8; j++) {
        const float v = p[c >> 1][8 * (c & 1) + j];
        const unsigned short hh2 = f2bf(v);
        ph[c][j] = (short)hh2;
        pl[c][j] = (short)f2bf(v - bf2f(hh2));
      }
    }

    // ---- O^T += V^T * P^T (split bf16, 24 MFMAs)
    __builtin_amdgcn_s_setprio(1);
#pragma unroll
    for (int t = 0; t < 2; t++) {
      const int row = 32 * t + lq;
#pragma unroll
      for (int c = 0; c < 4; c++) {
        const int idx = row * 64 + (((2 * c + hb) ^ (row & 7)) << 3);
        short8v vhf = *reinterpret_cast<const short8v*>(&Vh[idx]);
        short8v vlf = *reinterpret_cast<const short8v*>(&Vl[idx]);
        accO[t] = __builtin_amdgcn_mfma_f32_32x32x16_bf16(vhf, ph[c], accO[t], 0, 0, 0);
        accO[t] = __builtin_amdgcn_mfma_f32_32x32x16_bf16(vhf, pl[c], accO[t], 0, 0, 0);
        accO[t] = __builtin_amdgcn_mfma_f32_32x32x16_bf16(vlf, ph[c], accO[t], 0, 0, 0);
      }
    }
    __builtin_amdgcn_s_setprio(0);
    __syncthreads();
  }

  // ---- epilogue: O[q][d] = O^T[d][q] / l
  const float inv = 1.f / lrun;
  const size_t obase = (size_t)(bb * SEQ + qt * 128 + wv * 32 + lq) * D_MODEL + hd * 64;
#pragma unroll
  for (int t = 0; t < 2; t++)
#pragma unroll
    for (int r = 0; r < 16; r++) {
      const int d = 32 * t + (r & 3) + ((r >> 2) << 3) + 4 * hb;
      short hh2, ll2;
      split2(accO[t][r] * inv, hh2, ll2);
      oh[obase + d] = hh2;
      ol[obase + d] = ll2;
    }
}

// ---------------------------------------------------------------- fp32 GEMM (fallback)
template<bool RELU, bool RES>
__global__ __launch_bounds__(256)
void gemm_k(const float* __restrict__ A, int K, int Ncols,
            const float* __restrict__ W0, const float* __restrict__ W1p,
            const float* __restrict__ W2p,
            const float* __restrict__ B0, const float* __restrict__ B1p,
            const float* __restrict__ B2p,
            float* __restrict__ O0, float* __restrict__ O1p, float* __restrict__ O2p,
            int nbn_per, const float* __restrict__ resid)
{
  __shared__ float As[16][132];
  __shared__ float Bs[16][132];
  const int tid = threadIdx.x;
  const int split = blockIdx.x / nbn_per;
  const int bn = (blockIdx.x % nbn_per) * 128;
  const int bm = blockIdx.y * 128;
  const float* W  = split == 0 ? W0 : (split == 1 ? W1p : W2p);
  const float* Bi = split == 0 ? B0 : (split == 1 ? B1p : B2p);
  float* O        = split == 0 ? O0 : (split == 1 ? O1p : O2p);
  const int tx = tid & 15, ty = tid >> 4;

  float4 acc[2][4][2];
#pragma unroll
  for (int a = 0; a < 2; a++)
#pragma unroll
    for (int b = 0; b < 4; b++)
#pragma unroll
      for (int c = 0; c < 2; c++) acc[a][b][c] = make_float4(0.f, 0.f, 0.f, 0.f);

  for (int k0 = 0; k0 < K; k0 += 16) {
#pragma unroll
    for (int i = 0; i < 2; i++) {
      int p = tid + i * 256;
      int row = p >> 2, kk4 = (p & 3) << 2;
      float4 va = *reinterpret_cast<const float4*>(A + (size_t)(bm + row) * K + k0 + kk4);
      As[kk4 + 0][row] = va.x; As[kk4 + 1][row] = va.y;
      As[kk4 + 2][row] = va.z; As[kk4 + 3][row] = va.w;
    }
#pragma unroll
    for (int i = 0; i < 2; i++) {
      int p = tid + i * 256;
      int row = p >> 5, c4 = (p & 31) << 2;
      *reinterpret_cast<float4*>(&Bs[row][c4]) =
          *reinterpret_cast<const float4*>(W + (size_t)(k0 + row) * Ncols + bn + c4);
    }
    __syncthreads();
#pragma unroll
    for (int kk = 0; kk < 16; kk++) {
      float4 a0 = *reinterpret_cast<const float4*>(&As[kk][ty * 4]);
      float4 a1 = *reinterpret_cast<const float4*>(&As[kk][64 + ty * 4]);
      float4 b0 = *reinterpret_cast<const float4*>(&Bs[kk][tx * 4]);
      float4 b1 = *reinterpret_cast<const float4*>(&Bs[kk][64 + tx * 4]);
      float av0[4] = {a0.x, a0.y, a0.z, a0.w};
      float av1[4] = {a1.x, a1.y, a1.z, a1.w};
#pragma unroll
      for (int j = 0; j < 4; j++) {
        FMA4(acc[0][j][0], av0[j], b0); FMA4(acc[0][j][1], av0[j], b1);
        FMA4(acc[1][j][0], av1[j], b0); FMA4(acc[1][j][1], av1[j], b1);
      }
    }
    __syncthreads();
  }

#pragma unroll
  for (int ih = 0; ih < 2; ih++)
#pragma unroll
    for (int j = 0; j < 4; j++)
#pragma unroll
      for (int jh = 0; jh < 2; jh++) {
        int row = bm + ih * 64 + ty * 4 + j;
        int col = bn + jh * 64 + tx * 4;
        float4 r = acc[ih][j][jh];
        float4 bb = *reinterpret_cast<const float4*>(Bi + col);
        r.x += bb.x; r.y += bb.y; r.z += bb.z; r.w += bb.w;
        if (RES) {
          float4 rr = *reinterpret_cast<const float4*>(resid + (size_t)row * Ncols + col);
          r.x += rr.x; r.y += rr.y; r.z += rr.z; r.w += rr.w;
        }
        if (RELU) {
          r.x = fmaxf(r.x, 0.f); r.y = fmaxf(r.y, 0.f);
          r.z = fmaxf(r.z, 0.f); r.w = fmaxf(r.w, 0.f);
        }
        *reinterpret_cast<float4*>(O + (size_t)row * Ncols + col) = r;
      }
}

// ---------------------------------------------------------------- fp32 flash attn (fallback)
__global__ __launch_bounds__(256)
void attn_k(const float* __restrict__ Q, const float* __restrict__ K,
            const float* __restrict__ V, float* __restrict__ Og)
{
  __shared__ float QsT[64][132];
  __shared__ float KsT[64][68];
  __shared__ float Vs[64][68];
  __shared__ float Ps[128][68];

  const int tid = threadIdx.x, tx = tid & 15, ty = tid >> 4;
  const int bh = blockIdx.y;
  const int bb = bh >> 4, hd = bh & 15;
  const int qt = blockIdx.x;
  const float* Qp = Q + (size_t)(bb * SEQ + qt * 128) * D_MODEL + hd * 64;
  const float* Kp = K + (size_t)(bb * SEQ) * D_MODEL + hd * 64;
  const float* Vp = V + (size_t)(bb * SEQ) * D_MODEL + hd * 64;
  const size_t obase = (size_t)(bb * SEQ + qt * 128) * D_MODEL + hd * 64;

#pragma unroll
  for (int i = 0; i < 8; i++) {
    int p = tid + i * 256;
    int r = p >> 4, k4 = (p & 15) << 2;
    float4 va = *reinterpret_cast<const float4*>(Qp + (size_t)r * D_MODEL + k4);
    QsT[k4 + 0][r] = va.x; QsT[k4 + 1][r] = va.y;
    QsT[k4 + 2][r] = va.z; QsT[k4 + 3][r] = va.w;
  }

  float4 Oa[2][4];
  float mrun[2][4], lrun[2][4];
#pragma unroll
  for (int a = 0; a < 2; a++)
#pragma unroll
    for (int j = 0; j < 4; j++) {
      Oa[a][j] = make_float4(0.f, 0.f, 0.f, 0.f);
      mrun[a][j] = -1e30f; lrun[a][j] = 0.f;
    }

  __syncthreads();

  for (int kt = 0; kt < 32; kt++) {
#pragma unroll
    for (int i = 0; i < 4; i++) {
      int p = tid + i * 256;
      int r = p >> 4, k4 = (p & 15) << 2;
      float4 kv = *reinterpret_cast<const float4*>(Kp + (size_t)(kt * 64 + r) * D_MODEL + k4);
      KsT[k4 + 0][r] = kv.x; KsT[k4 + 1][r] = kv.y;
      KsT[k4 + 2][r] = kv.z; KsT[k4 + 3][r] = kv.w;
      float4 vv = *reinterpret_cast<const float4*>(Vp + (size_t)(kt * 64 + r) * D_MODEL + k4);
      *reinterpret_cast<float4*>(&Vs[r][k4]) = vv;
    }
    __syncthreads();

    float4 sc[2][4];
#pragma unroll
    for (int a = 0; a < 2; a++)
#pragma unroll
      for (int j = 0; j < 4; j++) sc[a][j] = make_float4(0.f, 0.f, 0.f, 0.f);

#pragma unroll 8
    for (int kk = 0; kk < 64; kk++) {
      float4 b0 = *reinterpret_cast<const float4*>(&KsT[kk][tx * 4]);
      float4 a0 = *reinterpret_cast<const float4*>(&QsT[kk][ty * 4]);
      float4 a1 = *reinterpret_cast<const float4*>(&QsT[kk][64 + ty * 4]);
      float av0[4] = {a0.x, a0.y, a0.z, a0.w};
      float av1[4] = {a1.x, a1.y, a1.z, a1.w};
#pragma unroll
      for (int j = 0; j < 4; j++) {
        FMA4(sc[0][j], av0[j], b0);
        FMA4(sc[1][j], av1[j], b0);
      }
    }

#pragma unroll
    for (int a = 0; a < 2; a++)
#pragma unroll
      for (int j = 0; j < 4; j++) {
        float4 s4 = sc[a][j];
        s4.x *= 0.125f; s4.y *= 0.125f; s4.z *= 0.125f; s4.w *= 0.125f;
        float tm = fmaxf(fmaxf(s4.x, s4.y), fmaxf(s4.z, s4.w));
#pragma unroll
        for (int o = 8; o > 0; o >>= 1) tm = fmaxf(tm, __shfl_xor(tm, o));
        float mnew = fmaxf(mrun[a][j], tm);
        float alpha = __expf(mrun[a][j] - mnew);
        float4 p;
        p.x = __expf(s4.x - mnew); p.y = __expf(s4.y - mnew);
        p.z = __expf(s4.z - mnew); p.w = __expf(s4.w - mnew);
        float ps = p.x + p.y + p.z + p.w;
#pragma unroll
        for (int o = 8; o > 0; o >>= 1) ps += __shfl_xor(ps, o);
        lrun[a][j] = lrun[a][j] * alpha + ps;
        mrun[a][j] = mnew;
        Oa[a][j].x *= alpha; Oa[a][j].y *= alpha;
        Oa[a][j].z *= alpha; Oa[a][j].w *= alpha;
        *reinterpret_cast<float4*>(&Ps[a * 64 + ty * 4 + j][tx * 4]) = p;
      }
    __syncthreads();

#pragma unroll 4
    for (int k4 = 0; k4 < 16; k4++) {
      float4 b[4];
#pragma unroll
      for (int u = 0; u < 4; u++)
        b[u] = *reinterpret_cast<const float4*>(&Vs[k4 * 4 + u][tx * 4]);
#pragma unroll
      for (int a = 0; a < 2; a++)
#pragma unroll
        for (int j = 0; j < 4; j++) {
          float4 p = *reinterpret_cast<const float4*>(&Ps[a * 64 + ty * 4 + j][k4 * 4]);
          FMA4(Oa[a][j], p.x, b[0]);
          FMA4(Oa[a][j], p.y, b[1]);
          FMA4(Oa[a][j], p.z, b[2]);
          FMA4(Oa[a][j], p.w, b[3]);
        }
    }
    __syncthreads();
  }

#pragma unroll
  for (int a = 0; a < 2; a++)
#pragma unroll
    for (int j = 0; j < 4; j++) {
      float inv = 1.f / lrun[a][j];
      float4 r = Oa[a][j];
      r.x *= inv; r.y *= inv; r.z *= inv; r.w *= inv;
      *reinterpret_cast<float4*>(Og + obase + (size_t)(a * 64 + ty * 4 + j) * D_MODEL + tx * 4) = r;
    }
}

// ---------------------------------------------------------------- launch
extern "C" void kernel_launch(void* const* d_in, const int* in_sizes, int n_in,
                              void* d_out, int out_size, void* d_ws, size_t ws_size,
                              hipStream_t stream)
{
  (void)in_sizes; (void)n_in; (void)out_size;
  const float* x    = (const float*)d_in[0];
  const float* Wq   = (const float*)d_in[1];
  const float* Wk   = (const float*)d_in[2];
  const float* Wv   = (const float*)d_in[3];
  const float* Wo   = (const float*)d_in[4];
  const float* bq   = (const float*)d_in[5];
  const float* bk   = (const float*)d_in[6];
  const float* bv   = (const float*)d_in[7];
  const float* bo   = (const float*)d_in[8];
  const float* W1   = (const float*)d_in[9];
  const float* b1   = (const float*)d_in[10];
  const float* W2   = (const float*)d_in[11];
  const float* b2   = (const float*)d_in[12];
  const float* ln1w = (const float*)d_in[13];
  const float* ln1b = (const float*)d_in[14];
  const float* ln2w = (const float*)d_in[15];
  const float* ln2b = (const float*)d_in[16];
  const float* lnfw = (const float*)d_in[17];
  const float* lnfb = (const float*)d_in[18];

  const size_t ND = (size_t)NTOK * D_MODEL;     // 4M
  const size_t M1 = 1024 * 1024;
  float* xb = (float*)d_out;

  hipMemcpyAsync(xb, x, sizeof(float) * ND, hipMemcpyDeviceToDevice, stream);

  const size_t REQ_MFMA = 184549376;            // 88M shorts = 176 MB
  const bool use_mfma = (ws_size >= REQ_MFMA);

  if (use_mfma) {
    short* wT_h = (short*)d_ws;                 // 12M shorts
    short* wT_l = wT_h + 12 * M1;
    short* h_hi = wT_l + 12 * M1;
    short* h_lo = h_hi + ND;
    short* q_hi = h_lo + ND;
    short* q_lo = q_hi + ND;
    short* k_hi = q_lo + ND;
    short* k_lo = k_hi + ND;
    short* vT_h = k_lo + ND;
    short* vT_l = vT_h + ND;
    short* t_hi = vT_l + ND;
    short* t_lo = t_hi + (size_t)NTOK * FF_DIM;

    for (int i = 0; i < LLAYERS; i++) {
      WPack p;
      p.src[0] = Wq + (size_t)i * M1; p.src[1] = Wk + (size_t)i * M1;
      p.src[2] = Wv + (size_t)i * M1; p.src[3] = Wo + (size_t)i * M1;
      p.src[4] = W1 + (size_t)i * D_MODEL * FF_DIM;
      p.src[5] = W2 + (size_t)i * FF_DIM * D_MODEL;
      for (int m = 0; m < 6; m++) {
        static const size_t doff[6] = {0, M1, 2 * M1, 3 * M1, 4 * M1, 8 * M1};
        p.dhi[m] = wT_h + doff[m]; p.dlo[m] = wT_l + doff[m];
      }
      p.K[0] = p.K[1] = p.K[2] = p.K[3] = 1024; p.K[4] = 1024; p.K[5] = 4096;
      p.N[0] = p.N[1] = p.N[2] = p.N[3] = 1024; p.N[4] = 4096; p.N[5] = 1024;
      cvtw_k<<<12288, 256, 0, stream>>>(p);

      ln_k<1><<<NTOK / 4, 256, 0, stream>>>(xb, ln1w + (size_t)i * D_MODEL,
                                            ln1b + (size_t)i * D_MODEL, nullptr, h_hi, h_lo);
      // fused QKV -> q/k hi/lo row-major, V -> phi-permuted V^T hi/lo
      mgemm_k<3><<<dim3(24, 32), 256, 0, stream>>>(
          h_hi, h_lo, 1024, 1024,
          wT_h, wT_l, wT_h + M1, wT_l + M1, wT_h + 2 * M1, wT_l + 2 * M1,
          bq + (size_t)i * D_MODEL, bk + (size_t)i * D_MODEL, bv + (size_t)i * D_MODEL,
          nullptr, nullptr, nullptr,
          q_hi, q_lo, k_hi, k_lo, vT_h, vT_l, 8, nullptr);
      mattn_k<<<dim3(16, 32), 256, 0, stream>>>(q_hi, q_lo, k_hi, k_lo, vT_h, vT_l, h_hi, h_lo);
      // x += attn @ Wo + bo
      mgemm_k<1><<<dim3(8, 32), 256, 0, stream>>>(
          h_hi, h_lo, 1024, 1024,
          wT_h + 3 * M1, wT_l + 3 * M1, wT_h + 3 * M1, wT_l + 3 * M1, wT_h + 3 * M1, wT_l + 3 * M1,
          bo + (size_t)i * D_MODEL, bo + (size_t)i * D_MODEL, bo + (size_t)i * D_MODEL,
          xb, xb, xb,
          nullptr, nullptr, nullptr, nullptr, nullptr, nullptr, 8, xb);
      ln_k<1><<<NTOK / 4, 256, 0, stream>>>(xb, ln2w + (size_t)i * D_MODEL,
                                            ln2b + (size_t)i * D_MODEL, nullptr, h_hi, h_lo);
      // t = relu(h @ W1 + b1) -> hi/lo
      mgemm_k<2><<<dim3(32, 32), 256, 0, stream>>>(
          h_hi, h_lo, 1024, 4096,
          wT_h + 4 * M1, wT_l + 4 * M1, wT_h + 4 * M1, wT_l + 4 * M1, wT_h + 4 * M1, wT_l + 4 * M1,
          b1 + (size_t)i * FF_DIM, b1 + (size_t)i * FF_DIM, b1 + (size_t)i * FF_DIM,
          nullptr, nullptr, nullptr,
          t_hi, t_lo, nullptr, nullptr, nullptr, nullptr, 32, nullptr);
      // x += t @ W2 + b2
      mgemm_k<1><<<dim3(8, 32), 256, 0, stream>>>(
          t_hi, t_lo, 4096, 1024,
          wT_h + 8 * M1, wT_l + 8 * M1, wT_h + 8 * M1, wT_l + 8 * M1, wT_h + 8 * M1, wT_l + 8 * M1,
          b2 + (size_t)i * D_MODEL, b2 + (size_t)i * D_MODEL, b2 + (size_t)i * D_MODEL,
          xb, xb, xb,
          nullptr, nullptr, nullptr, nullptr, nullptr, nullptr, 8, xb);
    }
    ln_k<0><<<NTOK / 4, 256, 0, stream>>>(xb, lnfw, lnfb, xb, nullptr, nullptr);
    return;
  }

  // ---------------- fallback: fp32 VALU path (needs 80MB ws) ----------------
  float* h  = (float*)d_ws;
  float* qb = h + ND;
  float* kb = qb + ND;
  float* vb = kb + ND;
  float* tb = qb;

  for (int i = 0; i < LLAYERS; i++) {
    const float* Wq_l = Wq + (size_t)i * M1;
    const float* Wk_l = Wk + (size_t)i * M1;
    const float* Wv_l = Wv + (size_t)i * M1;
    const float* Wo_l = Wo + (size_t)i * M1;
    const float* W1_l = W1 + (size_t)i * D_MODEL * FF_DIM;
    const float* W2_l = W2 + (size_t)i * FF_DIM * D_MODEL;

    ln_k<0><<<NTOK / 4, 256, 0, stream>>>(xb, ln1w + (size_t)i * D_MODEL,
                                          ln1b + (size_t)i * D_MODEL, h, nullptr, nullptr);
    gemm_k<false, false><<<dim3(24, 32), 256, 0, stream>>>(
        h, D_MODEL, D_MODEL, Wq_l, Wk_l, Wv_l,
        bq + (size_t)i * D_MODEL, bk + (size_t)i * D_MODEL, bv + (size_t)i * D_MODEL,
        qb, kb, vb, 8, nullptr);
    attn_k<<<dim3(16, 32), 256, 0, stream>>>(qb, kb, vb, h);
    gemm_k<false, true><<<dim3(8, 32), 256, 0, stream>>>(
        h, D_MODEL, D_MODEL, Wo_l, Wo_l, Wo_l,
        bo + (size_t)i * D_MODEL, bo + (size_t)i * D_MODEL, bo + (size_t)i * D_MODEL,
        xb, xb, xb, 8, xb);
    ln_k<0><<<NTOK / 4, 256, 0, stream>>>(xb, ln2w + (size_t)i * D_MODEL,
                                          ln2b + (size_t)i * D_MODEL, h, nullptr, nullptr);
    gemm_k<true, false><<<dim3(32, 32), 256, 0, stream>>>(
        h, D_MODEL, FF_DIM, W1_l, W1_l, W1_l,
        b1 + (size_t)i * FF_DIM, b1 + (size_t)i * FF_DIM, b1 + (size_t)i * FF_DIM,
        tb, tb, tb, 32, nullptr);
    gemm_k<false, true><<<dim3(8, 32), 256, 0, stream>>>(
        tb, FF_DIM, D_MODEL, W2_l, W2_l, W2_l,
        b2 + (size_t)i * D_MODEL, b2 + (size_t)i * D_MODEL, b2 + (size_t)i * D_MODEL,
        xb, xb, xb, 8, xb);
  }
  ln_k<0><<<NTOK / 4, 256, 0, stream>>>(xb, lnfw, lnfb, xb, nullptr, nullptr);
}

// Round 4
// 2293.229 us; speedup vs baseline: 1.9450x; 1.0481x over previous
//
#include <hip/hip_runtime.h>
#include <cstddef>
#include <cstdint>

// Transformer encoder fwd, MI355X. L=4, D=1024, H=16, DH=64, FF=4096, B=2, S=2048.
// Path A (ws >= 176MB): split-bf16 MFMA GEMMs (hi/lo, 3 MFMAs per fp32 product)
//   with global_load_lds staging (linear LDS dest, pre-swizzled global source),
//   + split-bf16 MFMA flash attention (swapped QK^T, in-lane softmax, reg-packed
//   P fragments against a phi-permuted global V^T layout).
// Path B (fallback): all-fp32 VALU implementation.

#define D_MODEL 1024
#define FF_DIM  4096
#define NTOK    4096
#define SEQ     2048
#define LLAYERS 4

using short8v = __attribute__((ext_vector_type(8))) short;   // 8 bf16 raw (4 VGPR)
using f32x16  = __attribute__((ext_vector_type(16))) float;  // 32x32 MFMA acc

#define FMA4(a_, s_, b_) { (a_).x += (s_)*(b_).x; (a_).y += (s_)*(b_).y; \
                           (a_).z += (s_)*(b_).z; (a_).w += (s_)*(b_).w; }

// ---------------------------------------------------------------- bf16 helpers
__device__ __forceinline__ unsigned short f2bf(float x) {
  unsigned int u = __float_as_uint(x);
  unsigned int r = u + 0x7fffu + ((u >> 16) & 1u);   // RNE; inputs finite
  return (unsigned short)(r >> 16);
}
__device__ __forceinline__ float bf2f(unsigned short h) {
  return __uint_as_float(((unsigned int)h) << 16);
}
__device__ __forceinline__ void split2(float x, short& hi, short& lo) {
  unsigned short h = f2bf(x);
  hi = (short)h;
  lo = (short)f2bf(x - bf2f(h));
}

// direct global->LDS DMA, 16B per lane (wave-uniform LDS base + lane*16)
__device__ __forceinline__ void gload16(const short* g, short* l) {
  __builtin_amdgcn_global_load_lds(
      (const __attribute__((address_space(1))) unsigned int*)g,
      (__attribute__((address_space(3))) unsigned int*)l, 16, 0, 0);
}

// ---------------------------------------------------------------- LayerNorm
template<int HILO>
__global__ __launch_bounds__(256)
void ln_k(const float* __restrict__ in, const float* __restrict__ w,
          const float* __restrict__ bia, float* __restrict__ outf,
          short* __restrict__ oh, short* __restrict__ ol)
{
  const int wv = threadIdx.x >> 6, lane = threadIdx.x & 63;
  const size_t row = (size_t)blockIdx.x * 4 + wv;
  const float4* x4 = reinterpret_cast<const float4*>(in + row * D_MODEL);
  float4 v[4];
  float s = 0.f;
#pragma unroll
  for (int i = 0; i < 4; i++) {
    v[i] = x4[lane + 64 * i];
    s += v[i].x + v[i].y + v[i].z + v[i].w;
  }
#pragma unroll
  for (int o = 32; o > 0; o >>= 1) s += __shfl_xor(s, o);
  const float mean = s * (1.f / D_MODEL);
  float qv = 0.f;
#pragma unroll
  for (int i = 0; i < 4; i++) {
    float a = v[i].x - mean, b = v[i].y - mean, c = v[i].z - mean, d = v[i].w - mean;
    qv += a * a + b * b + c * c + d * d;
  }
#pragma unroll
  for (int o = 32; o > 0; o >>= 1) qv += __shfl_xor(qv, o);
  const float rstd = rsqrtf(qv * (1.f / D_MODEL) + 1e-5f);
  const float4* w4 = reinterpret_cast<const float4*>(w);
  const float4* b4 = reinterpret_cast<const float4*>(bia);
#pragma unroll
  for (int i = 0; i < 4; i++) {
    float4 ww = w4[lane + 64 * i], bb = b4[lane + 64 * i], r;
    r.x = (v[i].x - mean) * rstd * ww.x + bb.x;
    r.y = (v[i].y - mean) * rstd * ww.y + bb.y;
    r.z = (v[i].z - mean) * rstd * ww.z + bb.z;
    r.w = (v[i].w - mean) * rstd * ww.w + bb.w;
    if (HILO) {
      short4 h, l;
      split2(r.x, h.x, l.x); split2(r.y, h.y, l.y);
      split2(r.z, h.z, l.z); split2(r.w, h.w, l.w);
      size_t off = row * D_MODEL + 4 * lane + 256 * i;
      *reinterpret_cast<short4*>(oh + off) = h;
      *reinterpret_cast<short4*>(ol + off) = l;
    } else {
      reinterpret_cast<float4*>(outf + row * D_MODEL)[lane + 64 * i] = r;
    }
  }
}

// ---------------------------------------------------------------- weight cvt
struct WPack {
  const float* src[6];
  short* dhi[6];
  short* dlo[6];
  int K[6], N[6];
};
__global__ __launch_bounds__(256)
void cvtw_k(WPack p)
{
  __shared__ float t[32][36];
  const int b = blockIdx.x;
  int m, tile;
  if (b < 4096)      { m = b >> 10; tile = b & 1023; }
  else if (b < 8192) { m = 4; tile = b - 4096; }
  else               { m = 5; tile = b - 8192; }
  const int K = p.K[m], N = p.N[m];
  const int sh = (m == 4) ? 7 : 5;
  const int k0 = (tile >> sh) * 32, n0 = (tile & ((1 << sh) - 1)) * 32;
  const int r = threadIdx.x >> 3, c4 = (threadIdx.x & 7) << 2;
  float4 v = *reinterpret_cast<const float4*>(p.src[m] + (size_t)(k0 + r) * N + n0 + c4);
  *reinterpret_cast<float4*>(&t[r][c4]) = v;
  __syncthreads();
  short4 h, l;
  split2(t[c4 + 0][r], h.x, l.x);
  split2(t[c4 + 1][r], h.y, l.y);
  split2(t[c4 + 2][r], h.z, l.z);
  split2(t[c4 + 3][r], h.w, l.w);
  size_t off = (size_t)(n0 + r) * K + k0 + c4;
  *reinterpret_cast<short4*>(p.dhi[m] + off) = h;
  *reinterpret_cast<short4*>(p.dlo[m] + off) = l;
}

// ---------------------------------------------------------------- MFMA GEMM
// C[M,Ncols] = epi(A @ B + bias); A hi/lo bf16 [M][K], B = W^T hi/lo bf16 [N][K].
// 128x128 tile, BK=64, 4 waves (2x2), wave tile 64x64 = 2x2 of 32x32 MFMAs,
// 3 MFMAs per product (ah*bh + ah*bl + al*bh), fp32 acc.
// Staging: global_load_lds width 16; wave w DMAs array w (Ah/Al/Bh/Bl), 16x1KB
// chunks; LDS dest linear, XOR swizzle baked into per-lane SOURCE granule
// (sg = (l&7) ^ (l>>3)), so LDS content == reg-staged layout; frag reads use
// slot ^ (row&7) as before. Compiler drains vmcnt(0) at the barrier (m97).
// MODE 0: fp32 out = acc+bias
// MODE 1: fp32 out = acc+bias+resid
// MODE 2: hi/lo out (OhA/OlA) = relu(acc+bias)
// MODE 3: QKV: split 0/1 -> row-major hi/lo (A/B pairs); split 2 -> V^T
//         phi-permuted scatter (C pair), layout [b*16+h][64 d][2048 rho(s)]
template<int MODE>
__global__ __launch_bounds__(256, 2)
void mgemm_k(const short* __restrict__ Ahg, const short* __restrict__ Alg,
             int K, int Ncols,
             const short* __restrict__ Wh0, const short* __restrict__ Wl0,
             const short* __restrict__ Wh1, const short* __restrict__ Wl1,
             const short* __restrict__ Wh2, const short* __restrict__ Wl2,
             const float* __restrict__ B0, const float* __restrict__ B1,
             const float* __restrict__ B2,
             float* __restrict__ O0, float* __restrict__ O1, float* __restrict__ O2,
             short* __restrict__ OhA, short* __restrict__ OlA,
             short* __restrict__ OhB, short* __restrict__ OlB,
             short* __restrict__ OhC, short* __restrict__ OlC,
             int nbn_per, const float* __restrict__ resid)
{
  __shared__ short Ash0[128 * 64];   // A hi
  __shared__ short Ash1[128 * 64];   // A lo
  __shared__ short Bsh0[128 * 64];   // B hi
  __shared__ short Bsh1[128 * 64];   // B lo
  const int tid = threadIdx.x;
  const int split = blockIdx.x / nbn_per;
  const int bn = (blockIdx.x % nbn_per) * 128;
  const int bm = blockIdx.y * 128;
  const short* Wh = split == 0 ? Wh0 : (split == 1 ? Wh1 : Wh2);
  const short* Wl = split == 0 ? Wl0 : (split == 1 ? Wl1 : Wl2);
  const float* Bi = split == 0 ? B0 : (split == 1 ? B1 : B2);
  float* Of       = split == 0 ? O0 : (split == 1 ? O1 : O2);
  const int l = tid & 63, w = tid >> 6;
  const int wr = w >> 1, wc = w & 1;

  // staging assignment: wave w owns one 16KB array
  short* sarr = (w == 0) ? Ash0 : (w == 1) ? Ash1 : (w == 2) ? Bsh0 : Bsh1;
  const short* gbase =
      (w == 0) ? Ahg + (size_t)bm * K :
      (w == 1) ? Alg + (size_t)bm * K :
      (w == 2) ? Wh + (size_t)bn * K :
                 Wl + (size_t)bn * K;
  // per-lane source offset within an 8-row chunk: row = l>>3, granule pre-
  // swizzled so linear LDS slot t holds global granule t ^ (row&7)
  const int loff = (l >> 3) * K + (((l & 7) ^ (l >> 3)) << 3);

  f32x16 acc[2][2];
#pragma unroll
  for (int a = 0; a < 2; a++)
#pragma unroll
    for (int b = 0; b < 2; b++)
#pragma unroll
      for (int i = 0; i < 16; i++) acc[a][b][i] = 0.f;

  for (int k0 = 0; k0 < K; k0 += 64) {
#pragma unroll
    for (int u = 0; u < 16; u++)
      gload16(gbase + k0 + u * 8 * K + loff, &sarr[u * 512]);
    __syncthreads();
#pragma unroll
    for (int ks = 0; ks < 4; ks++) {
      const int slot = (ks << 1) | (l >> 5);
      short8v afh[2], afl[2], bfh[2], bfl[2];
#pragma unroll
      for (int rt = 0; rt < 2; rt++) {
        int row = wr * 64 + rt * 32 + (l & 31);
        int ia = row * 64 + ((slot ^ (row & 7)) << 3);
        afh[rt] = *reinterpret_cast<const short8v*>(&Ash0[ia]);
        afl[rt] = *reinterpret_cast<const short8v*>(&Ash1[ia]);
        int col = wc * 64 + rt * 32 + (l & 31);
        int ib = col * 64 + ((slot ^ (col & 7)) << 3);
        bfh[rt] = *reinterpret_cast<const short8v*>(&Bsh0[ib]);
        bfl[rt] = *reinterpret_cast<const short8v*>(&Bsh1[ib]);
      }
#pragma unroll
      for (int rt = 0; rt < 2; rt++)
#pragma unroll
        for (int ct = 0; ct < 2; ct++) {
          acc[rt][ct] = __builtin_amdgcn_mfma_f32_32x32x16_bf16(afh[rt], bfh[ct], acc[rt][ct], 0, 0, 0);
          acc[rt][ct] = __builtin_amdgcn_mfma_f32_32x32x16_bf16(afh[rt], bfl[ct], acc[rt][ct], 0, 0, 0);
          acc[rt][ct] = __builtin_amdgcn_mfma_f32_32x32x16_bf16(afl[rt], bfh[ct], acc[rt][ct], 0, 0, 0);
        }
    }
    __syncthreads();
  }

  const int rbase = (l >> 5) * 4, cl = l & 31;
#pragma unroll
  for (int rt = 0; rt < 2; rt++)
#pragma unroll
    for (int ct = 0; ct < 2; ct++) {
      const int colg = bn + wc * 64 + ct * 32 + cl;
      const float bia = Bi[colg];
#pragma unroll
      for (int reg = 0; reg < 16; reg++) {
        const int rowg = bm + wr * 64 + rt * 32 + rbase + (reg & 3) + ((reg >> 2) << 3);
        float v = acc[rt][ct][reg] + bia;
        const size_t off = (size_t)rowg * Ncols + colg;
        if (MODE == 0) {
          Of[off] = v;
        } else if (MODE == 1) {
          Of[off] = v + resid[off];
        } else if (MODE == 2) {
          v = fmaxf(v, 0.f);
          short h, lo; split2(v, h, lo);
          OhA[off] = h; OlA[off] = lo;
        } else {  // MODE 3
          short h, lo; split2(v, h, lo);
          if (split < 2) {
            short* OH = split == 0 ? OhA : OhB;
            short* OL = split == 0 ? OlA : OlB;
            OH[off] = h; OL[off] = lo;
          } else {
            const int bbv = rowg >> 11, s = rowg & 2047;
            const int hdv = colg >> 6, dv = colg & 63;
            const int m = s & 15;
            const int pos = (m & 3) + ((m >> 3) << 2) + (((m >> 2) & 1) << 3);
            const size_t voff = ((size_t)(bbv * 16 + hdv) * 64 + dv) * SEQ + (s - m + pos);
            OhC[voff] = h; OlC[voff] = lo;
          }
        }
      }
    }
}

// ---------------------------------------------------------------- MFMA flash attention
// Block = (qtile of 128, b*16+h). 4 waves, each owns 32 q rows.
// S^T = mfma(A=K, B=Q): lane (q=l&31, hb=l>>5) holds S[q][kv], kv = 32t+(r&3)+8(r>>2)+4hb.
// P packed in-reg as B-frags with k-order phi(h,j)=(j&3)+8(j>>2)+4h;
// V^T pre-permuted globally (rho) so A-frags are contiguous b128 from swizzled LDS.
// O^T accum; epilogue scatters O[q][d] as hi/lo bf16.
__global__ __launch_bounds__(256)
void mattn_k(const short* __restrict__ qh, const short* __restrict__ ql,
             const short* __restrict__ kh, const short* __restrict__ kl,
             const short* __restrict__ vth, const short* __restrict__ vtl,
             short* __restrict__ oh, short* __restrict__ ol)
{
  __shared__ short Kh[64 * 64], Kl[64 * 64], Vh[64 * 64], Vl[64 * 64];  // 32 KB
  const int tid = threadIdx.x;
  const int l = tid & 63, wv = tid >> 6;
  const int lq = l & 31, hb = l >> 5;
  const int qt = blockIdx.x, bh = blockIdx.y;
  const int bb = bh >> 4, hd = bh & 15;

  // Q fragments: this wave's 32 q rows, 4 dh-chunks, hi/lo
  const size_t qoff = (size_t)(bb * SEQ + qt * 128 + wv * 32 + lq) * D_MODEL + hd * 64 + 8 * hb;
  short8v qfh[4], qfl[4];
#pragma unroll
  for (int c = 0; c < 4; c++) {
    qfh[c] = *reinterpret_cast<const short8v*>(qh + qoff + 16 * c);
    qfl[c] = *reinterpret_cast<const short8v*>(ql + qoff + 16 * c);
  }

  // staging: 2 granules (16B) per thread per array
  int dst[2];
  size_t kga[2], vga[2];
#pragma unroll
  for (int c = 0; c < 2; c++) {
    int g = tid + c * 256;
    int rr = g >> 3, ss = g & 7;
    dst[c] = rr * 64 + ((ss ^ (rr & 7)) << 3);
    kga[c] = (size_t)(bb * SEQ + rr) * D_MODEL + hd * 64 + ss * 8;
    vga[c] = (size_t)(bh * 64 + rr) * SEQ + ss * 8;
  }
  short8v skh[2], skl[2], svh[2], svl[2];
#pragma unroll
  for (int c = 0; c < 2; c++) {
    skh[c] = *reinterpret_cast<const short8v*>(kh + kga[c]);
    skl[c] = *reinterpret_cast<const short8v*>(kl + kga[c]);
    svh[c] = *reinterpret_cast<const short8v*>(vth + vga[c]);
    svl[c] = *reinterpret_cast<const short8v*>(vtl + vga[c]);
  }

  f32x16 accO[2];
#pragma unroll
  for (int t = 0; t < 2; t++)
#pragma unroll
    for (int i = 0; i < 16; i++) accO[t][i] = 0.f;
  float mrun = -3e38f, lrun = 0.f;

  for (int kt = 0; kt < 32; kt++) {
#pragma unroll
    for (int c = 0; c < 2; c++) {
      *reinterpret_cast<short8v*>(&Kh[dst[c]]) = skh[c];
      *reinterpret_cast<short8v*>(&Kl[dst[c]]) = skl[c];
      *reinterpret_cast<short8v*>(&Vh[dst[c]]) = svh[c];
      *reinterpret_cast<short8v*>(&Vl[dst[c]]) = svl[c];
    }
    __syncthreads();
    if (kt < 31) {                       // T14: issue next tile's loads early
#pragma unroll
      for (int c = 0; c < 2; c++) {
        size_t ko = kga[c] + (size_t)(kt + 1) * 64 * D_MODEL;
        size_t vo = vga[c] + (size_t)(kt + 1) * 64;
        skh[c] = *reinterpret_cast<const short8v*>(kh + ko);
        skl[c] = *reinterpret_cast<const short8v*>(kl + ko);
        svh[c] = *reinterpret_cast<const short8v*>(vth + vo);
        svl[c] = *reinterpret_cast<const short8v*>(vtl + vo);
      }
    }

    // ---- S^T = K * Q^T (split bf16, 24 MFMAs)
    f32x16 sc[2];
#pragma unroll
    for (int t = 0; t < 2; t++)
#pragma unroll
      for (int i = 0; i < 16; i++) sc[t][i] = 0.f;
    __builtin_amdgcn_s_setprio(1);
#pragma unroll
    for (int t = 0; t < 2; t++) {
      const int row = 32 * t + lq;
#pragma unroll
      for (int c = 0; c < 4; c++) {
        const int idx = row * 64 + (((2 * c + hb) ^ (row & 7)) << 3);
        short8v ah = *reinterpret_cast<const short8v*>(&Kh[idx]);
        short8v al = *reinterpret_cast<const short8v*>(&Kl[idx]);
        sc[t] = __builtin_amdgcn_mfma_f32_32x32x16_bf16(ah, qfh[c], sc[t], 0, 0, 0);
        sc[t] = __builtin_amdgcn_mfma_f32_32x32x16_bf16(ah, qfl[c], sc[t], 0, 0, 0);
        sc[t] = __builtin_amdgcn_mfma_f32_32x32x16_bf16(al, qfh[c], sc[t], 0, 0, 0);
      }
    }
    __builtin_amdgcn_s_setprio(0);

    // ---- online softmax (in-lane 32 values + cross-half shfl)
    float p[2][16];
    float tm = -3e38f;
#pragma unroll
    for (int t = 0; t < 2; t++)
#pragma unroll
      for (int r = 0; r < 16; r++) {
        p[t][r] = sc[t][r] * 0.125f;
        tm = fmaxf(tm, p[t][r]);
      }
    tm = fmaxf(tm, __shfl_xor(tm, 32));
    const float mnew = fmaxf(mrun, tm);
    const float alpha = __expf(mrun - mnew);
    float ps = 0.f;
#pragma unroll
    for (int t = 0; t < 2; t++)
#pragma unroll
      for (int r = 0; r < 16; r++) {
        p[t][r] = __expf(p[t][r] - mnew);
        ps += p[t][r];
      }
    ps += __shfl_xor(ps, 32);
    lrun = lrun * alpha + ps;
    mrun = mnew;
#pragma unroll
    for (int t = 0; t < 2; t++)
#pragma unroll
      for (int i = 0; i < 16; i++) accO[t][i] *= alpha;

    // ---- pack P hi/lo B-frags: chunk c <- p[c>>1][8*(c&1)+j]
    short8v ph[4], pl[4];
#pragma unroll
    for (int c = 0; c < 4; c++) {
#pragma unroll
      for (int j = 0; j < 8; j++) {
        const float v = p[c >> 1][8 * (c & 1) + j];
        const unsigned short hh2 = f2bf(v);
        ph[c][j] = (short)hh2;
        pl[c][j] = (short)f2bf(v - bf2f(hh2));
      }
    }

    // ---- O^T += V^T * P^T (split bf16, 24 MFMAs)
    __builtin_amdgcn_s_setprio(1);
#pragma unroll
    for (int t = 0; t < 2; t++) {
      const int row = 32 * t + lq;
#pragma unroll
      for (int c = 0; c < 4; c++) {
        const int idx = row * 64 + (((2 * c + hb) ^ (row & 7)) << 3);
        short8v vhf = *reinterpret_cast<const short8v*>(&Vh[idx]);
        short8v vlf = *reinterpret_cast<const short8v*>(&Vl[idx]);
        accO[t] = __builtin_amdgcn_mfma_f32_32x32x16_bf16(vhf, ph[c], accO[t], 0, 0, 0);
        accO[t] = __builtin_amdgcn_mfma_f32_32x32x16_bf16(vhf, pl[c], accO[t], 0, 0, 0);
        accO[t] = __builtin_amdgcn_mfma_f32_32x32x16_bf16(vlf, ph[c], accO[t], 0, 0, 0);
      }
    }
    __builtin_amdgcn_s_setprio(0);
    __syncthreads();
  }

  // ---- epilogue: O[q][d] = O^T[d][q] / l
  const float inv = 1.f / lrun;
  const size_t obase = (size_t)(bb * SEQ + qt * 128 + wv * 32 + lq) * D_MODEL + hd * 64;
#pragma unroll
  for (int t = 0; t < 2; t++)
#pragma unroll
    for (int r = 0; r < 16; r++) {
      const int d = 32 * t + (r & 3) + ((r >> 2) << 3) + 4 * hb;
      short hh2, ll2;
      split2(accO[t][r] * inv, hh2, ll2);
      oh[obase + d] = hh2;
      ol[obase + d] = ll2;
    }
}

// ---------------------------------------------------------------- fp32 GEMM (fallback)
template<bool RELU, bool RES>
__global__ __launch_bounds__(256)
void gemm_k(const float* __restrict__ A, int K, int Ncols,
            const float* __restrict__ W0, const float* __restrict__ W1p,
            const float* __restrict__ W2p,
            const float* __restrict__ B0, const float* __restrict__ B1p,
            const float* __restrict__ B2p,
            float* __restrict__ O0, float* __restrict__ O1p, float* __restrict__ O2p,
            int nbn_per, const float* __restrict__ resid)
{
  __shared__ float As[16][132];
  __shared__ float Bs[16][132];
  const int tid = threadIdx.x;
  const int split = blockIdx.x / nbn_per;
  const int bn = (blockIdx.x % nbn_per) * 128;
  const int bm = blockIdx.y * 128;
  const float* W  = split == 0 ? W0 : (split == 1 ? W1p : W2p);
  const float* Bi = split == 0 ? B0 : (split == 1 ? B1p : B2p);
  float* O        = split == 0 ? O0 : (split == 1 ? O1p : O2p);
  const int tx = tid & 15, ty = tid >> 4;

  float4 acc[2][4][2];
#pragma unroll
  for (int a = 0; a < 2; a++)
#pragma unroll
    for (int b = 0; b < 4; b++)
#pragma unroll
      for (int c = 0; c < 2; c++) acc[a][b][c] = make_float4(0.f, 0.f, 0.f, 0.f);

  for (int k0 = 0; k0 < K; k0 += 16) {
#pragma unroll
    for (int i = 0; i < 2; i++) {
      int p = tid + i * 256;
      int row = p >> 2, kk4 = (p & 3) << 2;
      float4 va = *reinterpret_cast<const float4*>(A + (size_t)(bm + row) * K + k0 + kk4);
      As[kk4 + 0][row] = va.x; As[kk4 + 1][row] = va.y;
      As[kk4 + 2][row] = va.z; As[kk4 + 3][row] = va.w;
    }
#pragma unroll
    for (int i = 0; i < 2; i++) {
      int p = tid + i * 256;
      int row = p >> 5, c4 = (p & 31) << 2;
      *reinterpret_cast<float4*>(&Bs[row][c4]) =
          *reinterpret_cast<const float4*>(W + (size_t)(k0 + row) * Ncols + bn + c4);
    }
    __syncthreads();
#pragma unroll
    for (int kk = 0; kk < 16; kk++) {
      float4 a0 = *reinterpret_cast<const float4*>(&As[kk][ty * 4]);
      float4 a1 = *reinterpret_cast<const float4*>(&As[kk][64 + ty * 4]);
      float4 b0 = *reinterpret_cast<const float4*>(&Bs[kk][tx * 4]);
      float4 b1 = *reinterpret_cast<const float4*>(&Bs[kk][64 + tx * 4]);
      float av0[4] = {a0.x, a0.y, a0.z, a0.w};
      float av1[4] = {a1.x, a1.y, a1.z, a1.w};
#pragma unroll
      for (int j = 0; j < 4; j++) {
        FMA4(acc[0][j][0], av0[j], b0); FMA4(acc[0][j][1], av0[j], b1);
        FMA4(acc[1][j][0], av1[j], b0); FMA4(acc[1][j][1], av1[j], b1);
      }
    }
    __syncthreads();
  }

#pragma unroll
  for (int ih = 0; ih < 2; ih++)
#pragma unroll
    for (int j = 0; j < 4; j++)
#pragma unroll
      for (int jh = 0; jh < 2; jh++) {
        int row = bm + ih * 64 + ty * 4 + j;
        int col = bn + jh * 64 + tx * 4;
        float4 r = acc[ih][j][jh];
        float4 bb = *reinterpret_cast<const float4*>(Bi + col);
        r.x += bb.x; r.y += bb.y; r.z += bb.z; r.w += bb.w;
        if (RES) {
          float4 rr = *reinterpret_cast<const float4*>(resid + (size_t)row * Ncols + col);
          r.x += rr.x; r.y += rr.y; r.z += rr.z; r.w += rr.w;
        }
        if (RELU) {
          r.x = fmaxf(r.x, 0.f); r.y = fmaxf(r.y, 0.f);
          r.z = fmaxf(r.z, 0.f); r.w = fmaxf(r.w, 0.f);
        }
        *reinterpret_cast<float4*>(O + (size_t)row * Ncols + col) = r;
      }
}

// ---------------------------------------------------------------- fp32 flash attn (fallback)
__global__ __launch_bounds__(256)
void attn_k(const float* __restrict__ Q, const float* __restrict__ K,
            const float* __restrict__ V, float* __restrict__ Og)
{
  __shared__ float QsT[64][132];
  __shared__ float KsT[64][68];
  __shared__ float Vs[64][68];
  __shared__ float Ps[128][68];

  const int tid = threadIdx.x, tx = tid & 15, ty = tid >> 4;
  const int bh = blockIdx.y;
  const int bb = bh >> 4, hd = bh & 15;
  const int qt = blockIdx.x;
  const float* Qp = Q + (size_t)(bb * SEQ + qt * 128) * D_MODEL + hd * 64;
  const float* Kp = K + (size_t)(bb * SEQ) * D_MODEL + hd * 64;
  const float* Vp = V + (size_t)(bb * SEQ) * D_MODEL + hd * 64;
  const size_t obase = (size_t)(bb * SEQ + qt * 128) * D_MODEL + hd * 64;

#pragma unroll
  for (int i = 0; i < 8; i++) {
    int p = tid + i * 256;
    int r = p >> 4, k4 = (p & 15) << 2;
    float4 va = *reinterpret_cast<const float4*>(Qp + (size_t)r * D_MODEL + k4);
    QsT[k4 + 0][r] = va.x; QsT[k4 + 1][r] = va.y;
    QsT[k4 + 2][r] = va.z; QsT[k4 + 3][r] = va.w;
  }

  float4 Oa[2][4];
  float mrun[2][4], lrun[2][4];
#pragma unroll
  for (int a = 0; a < 2; a++)
#pragma unroll
    for (int j = 0; j < 4; j++) {
      Oa[a][j] = make_float4(0.f, 0.f, 0.f, 0.f);
      mrun[a][j] = -1e30f; lrun[a][j] = 0.f;
    }

  __syncthreads();

  for (int kt = 0; kt < 32; kt++) {
#pragma unroll
    for (int i = 0; i < 4; i++) {
      int p = tid + i * 256;
      int r = p >> 4, k4 = (p & 15) << 2;
      float4 kv = *reinterpret_cast<const float4*>(Kp + (size_t)(kt * 64 + r) * D_MODEL + k4);
      KsT[k4 + 0][r] = kv.x; KsT[k4 + 1][r] = kv.y;
      KsT[k4 + 2][r] = kv.z; KsT[k4 + 3][r] = kv.w;
      float4 vv = *reinterpret_cast<const float4*>(Vp + (size_t)(kt * 64 + r) * D_MODEL + k4);
      *reinterpret_cast<float4*>(&Vs[r][k4]) = vv;
    }
    __syncthreads();

    float4 sc[2][4];
#pragma unroll
    for (int a = 0; a < 2; a++)
#pragma unroll
      for (int j = 0; j < 4; j++) sc[a][j] = make_float4(0.f, 0.f, 0.f, 0.f);

#pragma unroll 8
    for (int kk = 0; kk < 64; kk++) {
      float4 b0 = *reinterpret_cast<const float4*>(&KsT[kk][tx * 4]);
      float4 a0 = *reinterpret_cast<const float4*>(&QsT[kk][ty * 4]);
      float4 a1 = *reinterpret_cast<const float4*>(&QsT[kk][64 + ty * 4]);
      float av0[4] = {a0.x, a0.y, a0.z, a0.w};
      float av1[4] = {a1.x, a1.y, a1.z, a1.w};
#pragma unroll
      for (int j = 0; j < 4; j++) {
        FMA4(sc[0][j], av0[j], b0);
        FMA4(sc[1][j], av1[j], b0);
      }
    }

#pragma unroll
    for (int a = 0; a < 2; a++)
#pragma unroll
      for (int j = 0; j < 4; j++) {
        float4 s4 = sc[a][j];
        s4.x *= 0.125f; s4.y *= 0.125f; s4.z *= 0.125f; s4.w *= 0.125f;
        float tm = fmaxf(fmaxf(s4.x, s4.y), fmaxf(s4.z, s4.w));
#pragma unroll
        for (int o = 8; o > 0; o >>= 1) tm = fmaxf(tm, __shfl_xor(tm, o));
        float mnew = fmaxf(mrun[a][j], tm);
        float alpha = __expf(mrun[a][j] - mnew);
        float4 p;
        p.x = __expf(s4.x - mnew); p.y = __expf(s4.y - mnew);
        p.z = __expf(s4.z - mnew); p.w = __expf(s4.w - mnew);
        float ps = p.x + p.y + p.z + p.w;
#pragma unroll
        for (int o = 8; o > 0; o >>= 1) ps += __shfl_xor(ps, o);
        lrun[a][j] = lrun[a][j] * alpha + ps;
        mrun[a][j] = mnew;
        Oa[a][j].x *= alpha; Oa[a][j].y *= alpha;
        Oa[a][j].z *= alpha; Oa[a][j].w *= alpha;
        *reinterpret_cast<float4*>(&Ps[a * 64 + ty * 4 + j][tx * 4]) = p;
      }
    __syncthreads();

#pragma unroll 4
    for (int k4 = 0; k4 < 16; k4++) {
      float4 b[4];
#pragma unroll
      for (int u = 0; u < 4; u++)
        b[u] = *reinterpret_cast<const float4*>(&Vs[k4 * 4 + u][tx * 4]);
#pragma unroll
      for (int a = 0; a < 2; a++)
#pragma unroll
        for (int j = 0; j < 4; j++) {
          float4 p = *reinterpret_cast<const float4*>(&Ps[a * 64 + ty * 4 + j][k4 * 4]);
          FMA4(Oa[a][j], p.x, b[0]);
          FMA4(Oa[a][j], p.y, b[1]);
          FMA4(Oa[a][j], p.z, b[2]);
          FMA4(Oa[a][j], p.w, b[3]);
        }
    }
    __syncthreads();
  }

#pragma unroll
  for (int a = 0; a < 2; a++)
#pragma unroll
    for (int j = 0; j < 4; j++) {
      float inv = 1.f / lrun[a][j];
      float4 r = Oa[a][j];
      r.x *= inv; r.y *= inv; r.z *= inv; r.w *= inv;
      *reinterpret_cast<float4*>(Og + obase + (size_t)(a * 64 + ty * 4 + j) * D_MODEL + tx * 4) = r;
    }
}

// ---------------------------------------------------------------- launch
extern "C" void kernel_launch(void* const* d_in, const int* in_sizes, int n_in,
                              void* d_out, int out_size, void* d_ws, size_t ws_size,
                              hipStream_t stream)
{
  (void)in_sizes; (void)n_in; (void)out_size;
  const float* x    = (const float*)d_in[0];
  const float* Wq   = (const float*)d_in[1];
  const float* Wk   = (const float*)d_in[2];
  const float* Wv   = (const float*)d_in[3];
  const float* Wo   = (const float*)d_in[4];
  const float* bq   = (const float*)d_in[5];
  const float* bk   = (const float*)d_in[6];
  const float* bv   = (const float*)d_in[7];
  const float* bo   = (const float*)d_in[8];
  const float* W1   = (const float*)d_in[9];
  const float* b1   = (const float*)d_in[10];
  const float* W2   = (const float*)d_in[11];
  const float* b2   = (const float*)d_in[12];
  const float* ln1w = (const float*)d_in[13];
  const float* ln1b = (const float*)d_in[14];
  const float* ln2w = (const float*)d_in[15];
  const float* ln2b = (const float*)d_in[16];
  const float* lnfw = (const float*)d_in[17];
  const float* lnfb = (const float*)d_in[18];

  const size_t ND = (size_t)NTOK * D_MODEL;     // 4M
  const size_t M1 = 1024 * 1024;
  float* xb = (float*)d_out;

  hipMemcpyAsync(xb, x, sizeof(float) * ND, hipMemcpyDeviceToDevice, stream);

  const size_t REQ_MFMA = 184549376;            // 88M shorts = 176 MB
  const bool use_mfma = (ws_size >= REQ_MFMA);

  if (use_mfma) {
    short* wT_h = (short*)d_ws;                 // 12M shorts
    short* wT_l = wT_h + 12 * M1;
    short* h_hi = wT_l + 12 * M1;
    short* h_lo = h_hi + ND;
    short* q_hi = h_lo + ND;
    short* q_lo = q_hi + ND;
    short* k_hi = q_lo + ND;
    short* k_lo = k_hi + ND;
    short* vT_h = k_lo + ND;
    short* vT_l = vT_h + ND;
    short* t_hi = vT_l + ND;
    short* t_lo = t_hi + (size_t)NTOK * FF_DIM;

    for (int i = 0; i < LLAYERS; i++) {
      WPack p;
      p.src[0] = Wq + (size_t)i * M1; p.src[1] = Wk + (size_t)i * M1;
      p.src[2] = Wv + (size_t)i * M1; p.src[3] = Wo + (size_t)i * M1;
      p.src[4] = W1 + (size_t)i * D_MODEL * FF_DIM;
      p.src[5] = W2 + (size_t)i * FF_DIM * D_MODEL;
      for (int m = 0; m < 6; m++) {
        static const size_t doff[6] = {0, M1, 2 * M1, 3 * M1, 4 * M1, 8 * M1};
        p.dhi[m] = wT_h + doff[m]; p.dlo[m] = wT_l + doff[m];
      }
      p.K[0] = p.K[1] = p.K[2] = p.K[3] = 1024; p.K[4] = 1024; p.K[5] = 4096;
      p.N[0] = p.N[1] = p.N[2] = p.N[3] = 1024; p.N[4] = 4096; p.N[5] = 1024;
      cvtw_k<<<12288, 256, 0, stream>>>(p);

      ln_k<1><<<NTOK / 4, 256, 0, stream>>>(xb, ln1w + (size_t)i * D_MODEL,
                                            ln1b + (size_t)i * D_MODEL, nullptr, h_hi, h_lo);
      // fused QKV -> q/k hi/lo row-major, V -> phi-permuted V^T hi/lo
      mgemm_k<3><<<dim3(24, 32), 256, 0, stream>>>(
          h_hi, h_lo, 1024, 1024,
          wT_h, wT_l, wT_h + M1, wT_l + M1, wT_h + 2 * M1, wT_l + 2 * M1,
          bq + (size_t)i * D_MODEL, bk + (size_t)i * D_MODEL, bv + (size_t)i * D_MODEL,
          nullptr, nullptr, nullptr,
          q_hi, q_lo, k_hi, k_lo, vT_h, vT_l, 8, nullptr);
      mattn_k<<<dim3(16, 32), 256, 0, stream>>>(q_hi, q_lo, k_hi, k_lo, vT_h, vT_l, h_hi, h_lo);
      // x += attn @ Wo + bo
      mgemm_k<1><<<dim3(8, 32), 256, 0, stream>>>(
          h_hi, h_lo, 1024, 1024,
          wT_h + 3 * M1, wT_l + 3 * M1, wT_h + 3 * M1, wT_l + 3 * M1, wT_h + 3 * M1, wT_l + 3 * M1,
          bo + (size_t)i * D_MODEL, bo + (size_t)i * D_MODEL, bo + (size_t)i * D_MODEL,
          xb, xb, xb,
          nullptr, nullptr, nullptr, nullptr, nullptr, nullptr, 8, xb);
      ln_k<1><<<NTOK / 4, 256, 0, stream>>>(xb, ln2w + (size_t)i * D_MODEL,
                                            ln2b + (size_t)i * D_MODEL, nullptr, h_hi, h_lo);
      // t = relu(h @ W1 + b1) -> hi/lo
      mgemm_k<2><<<dim3(32, 32), 256, 0, stream>>>(
          h_hi, h_lo, 1024, 4096,
          wT_h + 4 * M1, wT_l + 4 * M1, wT_h + 4 * M1, wT_l + 4 * M1, wT_h + 4 * M1, wT_l + 4 * M1,
          b1 + (size_t)i * FF_DIM, b1 + (size_t)i * FF_DIM, b1 + (size_t)i * FF_DIM,
          nullptr, nullptr, nullptr,
          t_hi, t_lo, nullptr, nullptr, nullptr, nullptr, 32, nullptr);
      // x += t @ W2 + b2
      mgemm_k<1><<<dim3(8, 32), 256, 0, stream>>>(
          t_hi, t_lo, 4096, 1024,
          wT_h + 8 * M1, wT_l + 8 * M1, wT_h + 8 * M1, wT_l + 8 * M1, wT_h + 8 * M1, wT_l + 8 * M1,
          b2 + (size_t)i * D_MODEL, b2 + (size_t)i * D_MODEL, b2 + (size_t)i * D_MODEL,
          xb, xb, xb,
          nullptr, nullptr, nullptr, nullptr, nullptr, nullptr, 8, xb);
    }
    ln_k<0><<<NTOK / 4, 256, 0, stream>>>(xb, lnfw, lnfb, xb, nullptr, nullptr);
    return;
  }

  // ---------------- fallback: fp32 VALU path (needs 80MB ws) ----------------
  float* h  = (float*)d_ws;
  float* qb = h + ND;
  float* kb = qb + ND;
  float* vb = kb + ND;
  float* tb = qb;

  for (int i = 0; i < LLAYERS; i++) {
    const float* Wq_l = Wq + (size_t)i * M1;
    const float* Wk_l = Wk + (size_t)i * M1;
    const float* Wv_l = Wv + (size_t)i * M1;
    const float* Wo_l = Wo + (size_t)i * M1;
    const float* W1_l = W1 + (size_t)i * D_MODEL * FF_DIM;
    const float* W2_l = W2 + (size_t)i * FF_DIM * D_MODEL;

    ln_k<0><<<NTOK / 4, 256, 0, stream>>>(xb, ln1w + (size_t)i * D_MODEL,
                                          ln1b + (size_t)i * D_MODEL, h, nullptr, nullptr);
    gemm_k<false, false><<<dim3(24, 32), 256, 0, stream>>>(
        h, D_MODEL, D_MODEL, Wq_l, Wk_l, Wv_l,
        bq + (size_t)i * D_MODEL, bk + (size_t)i * D_MODEL, bv + (size_t)i * D_MODEL,
        qb, kb, vb, 8, nullptr);
    attn_k<<<dim3(16, 32), 256, 0, stream>>>(qb, kb, vb, h);
    gemm_k<false, true><<<dim3(8, 32), 256, 0, stream>>>(
        h, D_MODEL, D_MODEL, Wo_l, Wo_l, Wo_l,
        bo + (size_t)i * D_MODEL, bo + (size_t)i * D_MODEL, bo + (size_t)i * D_MODEL,
        xb, xb, xb, 8, xb);
    ln_k<0><<<NTOK / 4, 256, 0, stream>>>(xb, ln2w + (size_t)i * D_MODEL,
                                          ln2b + (size_t)i * D_MODEL, h, nullptr, nullptr);
    gemm_k<true, false><<<dim3(32, 32), 256, 0, stream>>>(
        h, D_MODEL, FF_DIM, W1_l, W1_l, W1_l,
        b1 + (size_t)i * FF_DIM, b1 + (size_t)i * FF_DIM, b1 + (size_t)i * FF_DIM,
        tb, tb, tb, 32, nullptr);
    gemm_k<false, true><<<dim3(8, 32), 256, 0, stream>>>(
        tb, FF_DIM, D_MODEL, W2_l, W2_l, W2_l,
        b2 + (size_t)i * D_MODEL, b2 + (size_t)i * D_MODEL, b2 + (size_t)i * D_MODEL,
        xb, xb, xb, 8, xb);
  }
  ln_k<0><<<NTOK / 4, 256, 0, stream>>>(xb, lnfw, lnfb, xb, nullptr, nullptr);
}

// Round 5
// 2233.667 us; speedup vs baseline: 1.9969x; 1.0267x over previous
//
#include <hip/hip_runtime.h>
#include <cstddef>
#include <cstdint>

// Transformer encoder fwd, MI355X. L=4, D=1024, H=16, DH=64, FF=4096, B=2, S=2048.
// Path A (ws >= 176MB): split-bf16 MFMA GEMMs (hi/lo, 3 MFMAs per fp32 product),
//   2-phase double-buffered global_load_lds staging + bijective XCD block swizzle,
//   + split-bf16 MFMA flash attention (swapped QK^T, in-lane exp2 softmax with
//   defer-max, single-bf16 P against split V^T).
// Path B (fallback): all-fp32 VALU implementation.

#define D_MODEL 1024
#define FF_DIM  4096
#define NTOK    4096
#define SEQ     2048
#define LLAYERS 4
#define QSCALE  0.180336880111f   // 0.125 * log2(e): folded into Q -> softmax uses exp2

using short8v = __attribute__((ext_vector_type(8))) short;   // 8 bf16 raw (4 VGPR)
using f32x16  = __attribute__((ext_vector_type(16))) float;  // 32x32 MFMA acc

#define FMA4(a_, s_, b_) { (a_).x += (s_)*(b_).x; (a_).y += (s_)*(b_).y; \
                           (a_).z += (s_)*(b_).z; (a_).w += (s_)*(b_).w; }

// ---------------------------------------------------------------- bf16 helpers
__device__ __forceinline__ unsigned short f2bf(float x) {
  unsigned int u = __float_as_uint(x);
  unsigned int r = u + 0x7fffu + ((u >> 16) & 1u);   // RNE; inputs finite
  return (unsigned short)(r >> 16);
}
__device__ __forceinline__ float bf2f(unsigned short h) {
  return __uint_as_float(((unsigned int)h) << 16);
}
__device__ __forceinline__ void split2(float x, short& hi, short& lo) {
  unsigned short h = f2bf(x);
  hi = (short)h;
  lo = (short)f2bf(x - bf2f(h));
}

// direct global->LDS DMA, 16B per lane (wave-uniform LDS base + lane*16)
__device__ __forceinline__ void gload16(const short* g, short* l) {
  __builtin_amdgcn_global_load_lds(
      (const __attribute__((address_space(1))) unsigned int*)g,
      (__attribute__((address_space(3))) unsigned int*)l, 16, 0, 0);
}

// ---------------------------------------------------------------- LayerNorm
template<int HILO>
__global__ __launch_bounds__(256)
void ln_k(const float* __restrict__ in, const float* __restrict__ w,
          const float* __restrict__ bia, float* __restrict__ outf,
          short* __restrict__ oh, short* __restrict__ ol)
{
  const int wv = threadIdx.x >> 6, lane = threadIdx.x & 63;
  const size_t row = (size_t)blockIdx.x * 4 + wv;
  const float4* x4 = reinterpret_cast<const float4*>(in + row * D_MODEL);
  float4 v[4];
  float s = 0.f;
#pragma unroll
  for (int i = 0; i < 4; i++) {
    v[i] = x4[lane + 64 * i];
    s += v[i].x + v[i].y + v[i].z + v[i].w;
  }
#pragma unroll
  for (int o = 32; o > 0; o >>= 1) s += __shfl_xor(s, o);
  const float mean = s * (1.f / D_MODEL);
  float qv = 0.f;
#pragma unroll
  for (int i = 0; i < 4; i++) {
    float a = v[i].x - mean, b = v[i].y - mean, c = v[i].z - mean, d = v[i].w - mean;
    qv += a * a + b * b + c * c + d * d;
  }
#pragma unroll
  for (int o = 32; o > 0; o >>= 1) qv += __shfl_xor(qv, o);
  const float rstd = rsqrtf(qv * (1.f / D_MODEL) + 1e-5f);
  const float4* w4 = reinterpret_cast<const float4*>(w);
  const float4* b4 = reinterpret_cast<const float4*>(bia);
#pragma unroll
  for (int i = 0; i < 4; i++) {
    float4 ww = w4[lane + 64 * i], bb = b4[lane + 64 * i], r;
    r.x = (v[i].x - mean) * rstd * ww.x + bb.x;
    r.y = (v[i].y - mean) * rstd * ww.y + bb.y;
    r.z = (v[i].z - mean) * rstd * ww.z + bb.z;
    r.w = (v[i].w - mean) * rstd * ww.w + bb.w;
    if (HILO) {
      short4 h, l;
      split2(r.x, h.x, l.x); split2(r.y, h.y, l.y);
      split2(r.z, h.z, l.z); split2(r.w, h.w, l.w);
      size_t off = row * D_MODEL + 4 * lane + 256 * i;
      *reinterpret_cast<short4*>(oh + off) = h;
      *reinterpret_cast<short4*>(ol + off) = l;
    } else {
      reinterpret_cast<float4*>(outf + row * D_MODEL)[lane + 64 * i] = r;
    }
  }
}

// ---------------------------------------------------------------- weight cvt
struct WPack {
  const float* src[6];
  short* dhi[6];
  short* dlo[6];
  int K[6], N[6];
};
__global__ __launch_bounds__(256)
void cvtw_k(WPack p)
{
  __shared__ float t[32][36];
  const int b = blockIdx.x;
  int m, tile;
  if (b < 4096)      { m = b >> 10; tile = b & 1023; }
  else if (b < 8192) { m = 4; tile = b - 4096; }
  else               { m = 5; tile = b - 8192; }
  const int K = p.K[m], N = p.N[m];
  const int sh = (m == 4) ? 7 : 5;
  const int k0 = (tile >> sh) * 32, n0 = (tile & ((1 << sh) - 1)) * 32;
  const int r = threadIdx.x >> 3, c4 = (threadIdx.x & 7) << 2;
  float4 v = *reinterpret_cast<const float4*>(p.src[m] + (size_t)(k0 + r) * N + n0 + c4);
  *reinterpret_cast<float4*>(&t[r][c4]) = v;
  __syncthreads();
  short4 h, l;
  split2(t[c4 + 0][r], h.x, l.x);
  split2(t[c4 + 1][r], h.y, l.y);
  split2(t[c4 + 2][r], h.z, l.z);
  split2(t[c4 + 3][r], h.w, l.w);
  size_t off = (size_t)(n0 + r) * K + k0 + c4;
  *reinterpret_cast<short4*>(p.dhi[m] + off) = h;
  *reinterpret_cast<short4*>(p.dlo[m] + off) = l;
}

// ---------------------------------------------------------------- MFMA GEMM
// C[M,Ncols] = epi(A @ B + bias); A hi/lo bf16 [M][K], B = W^T hi/lo bf16 [N][K].
// 128x128 tile, BK=64, 4 waves (2x2), wave tile 64x64 = 2x2 of 32x32 MFMAs,
// 3 MFMAs per product (ah*bh + ah*bl + al*bh), fp32 acc.
// 2-phase double-buffered staging: per iter {barrier; STAGE(buf^1, next);
// compute(buf)} -- the barrier's vmcnt(0) drains loads issued one full compute
// phase earlier, so the DMA latency hides under MFMA+ds_read (T3 minimum form).
// Bijective XCD block swizzle (T1/m204): consecutive same-XCD blocks share the
// A-panel for L2 locality. All grids have nwg % 8 == 0.
// MODE 0: fp32 out = acc+bias
// MODE 1: fp32 out = acc+bias+resid
// MODE 2: hi/lo out (OhA/OlA) = relu(acc+bias)
// MODE 3: QKV: split 0 -> Q scaled by QSCALE, row-major hi/lo (A pair);
//         split 1 -> K row-major hi/lo (B pair); split 2 -> V^T phi-permuted
//         scatter (C pair), layout [b*16+h][64 d][2048 rho(s)]
template<int MODE>
__global__ __launch_bounds__(256, 1)
void mgemm_k(const short* __restrict__ Ahg, const short* __restrict__ Alg,
             int K, int Ncols,
             const short* __restrict__ Wh0, const short* __restrict__ Wl0,
             const short* __restrict__ Wh1, const short* __restrict__ Wl1,
             const short* __restrict__ Wh2, const short* __restrict__ Wl2,
             const float* __restrict__ B0, const float* __restrict__ B1,
             const float* __restrict__ B2,
             float* __restrict__ O0, float* __restrict__ O1, float* __restrict__ O2,
             short* __restrict__ OhA, short* __restrict__ OlA,
             short* __restrict__ OhB, short* __restrict__ OlB,
             short* __restrict__ OhC, short* __restrict__ OlC,
             int nbn_per, const float* __restrict__ resid)
{
  __shared__ short buf[2][4][128 * 64];   // [dbuf][Ah,Al,Bh,Bl] = 128 KB
  const int tid = threadIdx.x;

  // bijective XCD chunking (nwg % 8 == 0 for all launches)
  const int gx = gridDim.x;
  const int nwg = gx * gridDim.y;
  const int g = blockIdx.y * gx + blockIdx.x;
  const int lg = (g & 7) * (nwg >> 3) + (g >> 3);
  const int bxs = lg % gx, bys = lg / gx;

  const int split = bxs / nbn_per;
  const int bn = (bxs % nbn_per) * 128;
  const int bm = bys * 128;
  const short* Wh = split == 0 ? Wh0 : (split == 1 ? Wh1 : Wh2);
  const short* Wl = split == 0 ? Wl0 : (split == 1 ? Wl1 : Wl2);
  const float* Bi = split == 0 ? B0 : (split == 1 ? B1 : B2);
  float* Of       = split == 0 ? O0 : (split == 1 ? O1 : O2);
  const int l = tid & 63, w = tid >> 6;
  const int wr = w >> 1, wc = w & 1;

  // staging: wave w owns one array; linear LDS dest, XOR swizzle pre-baked
  // into per-lane SOURCE granule (granule = (l&7) ^ (l>>3) within 8-row chunk)
  const short* gbase =
      (w == 0) ? Ahg + (size_t)bm * K :
      (w == 1) ? Alg + (size_t)bm * K :
      (w == 2) ? Wh + (size_t)bn * K :
                 Wl + (size_t)bn * K;
  const int loff = (l >> 3) * K + (((l & 7) ^ (l >> 3)) << 3);

  f32x16 acc[2][2];
#pragma unroll
  for (int a = 0; a < 2; a++)
#pragma unroll
    for (int b = 0; b < 2; b++)
#pragma unroll
      for (int i = 0; i < 16; i++) acc[a][b][i] = 0.f;

  const int nt = K >> 6;
  // prologue: stage tile 0 into buf 0
  {
    const short* g0 = gbase + loff;
    short* s0 = &buf[0][w][0];
#pragma unroll
    for (int u = 0; u < 16; u++) gload16(g0 + u * 8 * K, s0 + u * 512);
  }
  int p = 0;
  for (int t = 0; t < nt; ++t) {
    __syncthreads();                       // vmcnt(0): buf[p] ready; buf[p^1] free
    if (t + 1 < nt) {
      const short* g0 = gbase + ((t + 1) << 6) + loff;
      short* s0 = &buf[p ^ 1][w][0];
#pragma unroll
      for (int u = 0; u < 16; u++) gload16(g0 + u * 8 * K, s0 + u * 512);
    }
    const short* Ah = &buf[p][0][0];
    const short* Al = &buf[p][1][0];
    const short* Bh = &buf[p][2][0];
    const short* Bl = &buf[p][3][0];
#pragma unroll
    for (int ks = 0; ks < 4; ks++) {
      const int slot = (ks << 1) | (l >> 5);
      short8v afh[2], afl[2], bfh[2], bfl[2];
#pragma unroll
      for (int rt = 0; rt < 2; rt++) {
        int row = wr * 64 + rt * 32 + (l & 31);
        int ia = row * 64 + ((slot ^ (row & 7)) << 3);
        afh[rt] = *reinterpret_cast<const short8v*>(&Ah[ia]);
        afl[rt] = *reinterpret_cast<const short8v*>(&Al[ia]);
        int col = wc * 64 + rt * 32 + (l & 31);
        int ib = col * 64 + ((slot ^ (col & 7)) << 3);
        bfh[rt] = *reinterpret_cast<const short8v*>(&Bh[ib]);
        bfl[rt] = *reinterpret_cast<const short8v*>(&Bl[ib]);
      }
#pragma unroll
      for (int rt = 0; rt < 2; rt++)
#pragma unroll
        for (int ct = 0; ct < 2; ct++) {
          acc[rt][ct] = __builtin_amdgcn_mfma_f32_32x32x16_bf16(afh[rt], bfh[ct], acc[rt][ct], 0, 0, 0);
          acc[rt][ct] = __builtin_amdgcn_mfma_f32_32x32x16_bf16(afh[rt], bfl[ct], acc[rt][ct], 0, 0, 0);
          acc[rt][ct] = __builtin_amdgcn_mfma_f32_32x32x16_bf16(afl[rt], bfh[ct], acc[rt][ct], 0, 0, 0);
        }
    }
    p ^= 1;
  }

  const int rbase = (l >> 5) * 4, cl = l & 31;
#pragma unroll
  for (int rt = 0; rt < 2; rt++)
#pragma unroll
    for (int ct = 0; ct < 2; ct++) {
      const int colg = bn + wc * 64 + ct * 32 + cl;
      const float bia = Bi[colg];
#pragma unroll
      for (int reg = 0; reg < 16; reg++) {
        const int rowg = bm + wr * 64 + rt * 32 + rbase + (reg & 3) + ((reg >> 2) << 3);
        float v = acc[rt][ct][reg] + bia;
        const size_t off = (size_t)rowg * Ncols + colg;
        if (MODE == 0) {
          Of[off] = v;
        } else if (MODE == 1) {
          Of[off] = v + resid[off];
        } else if (MODE == 2) {
          v = fmaxf(v, 0.f);
          short h, lo; split2(v, h, lo);
          OhA[off] = h; OlA[off] = lo;
        } else {  // MODE 3
          if (split == 0) v *= QSCALE;     // fold softmax scale*log2e into Q
          short h, lo; split2(v, h, lo);
          if (split < 2) {
            short* OH = split == 0 ? OhA : OhB;
            short* OL = split == 0 ? OlA : OlB;
            OH[off] = h; OL[off] = lo;
          } else {
            const int bbv = rowg >> 11, s = rowg & 2047;
            const int hdv = colg >> 6, dv = colg & 63;
            const int m = s & 15;
            const int pos = (m & 3) + ((m >> 3) << 2) + (((m >> 2) & 1) << 3);
            const size_t voff = ((size_t)(bbv * 16 + hdv) * 64 + dv) * SEQ + (s - m + pos);
            OhC[voff] = h; OlC[voff] = lo;
          }
        }
      }
    }
}

// ---------------------------------------------------------------- MFMA flash attention
// Block = (qtile of 128, b*16+h). 4 waves, each owns 32 q rows.
// S^T = mfma(A=K, B=Q) with Q pre-scaled by 0.125*log2e -> softmax = exp2.
// Lane (q=l&31, hb=l>>5) holds S[q][kv], kv = 32t+(r&3)+8(r>>2)+4hb.
// Defer-max (T13, THR=8): skip O/l rescale while per-tile max growth <= 8.
// P packed as SINGLE bf16 B-frag (k-order phi(h,j)=(j&3)+8(j>>2)+4h);
// V^T pre-permuted globally so A-frags are contiguous b128 from swizzled LDS.
// PV = mfma(vh,ph) + mfma(vl,ph). O^T accum; epilogue scatters O[q][d] hi/lo.
__global__ __launch_bounds__(256)
void mattn_k(const short* __restrict__ qh, const short* __restrict__ ql,
             const short* __restrict__ kh, const short* __restrict__ kl,
             const short* __restrict__ vth, const short* __restrict__ vtl,
             short* __restrict__ oh, short* __restrict__ ol)
{
  __shared__ short Kh[64 * 64], Kl[64 * 64], Vh[64 * 64], Vl[64 * 64];  // 32 KB
  const int tid = threadIdx.x;
  const int l = tid & 63, wv = tid >> 6;
  const int lq = l & 31, hb = l >> 5;
  const int qt = blockIdx.x, bh = blockIdx.y;
  const int bb = bh >> 4, hd = bh & 15;

  const size_t qoff = (size_t)(bb * SEQ + qt * 128 + wv * 32 + lq) * D_MODEL + hd * 64 + 8 * hb;
  short8v qfh[4], qfl[4];
#pragma unroll
  for (int c = 0; c < 4; c++) {
    qfh[c] = *reinterpret_cast<const short8v*>(qh + qoff + 16 * c);
    qfl[c] = *reinterpret_cast<const short8v*>(ql + qoff + 16 * c);
  }

  int dst[2];
  size_t kga[2], vga[2];
#pragma unroll
  for (int c = 0; c < 2; c++) {
    int g = tid + c * 256;
    int rr = g >> 3, ss = g & 7;
    dst[c] = rr * 64 + ((ss ^ (rr & 7)) << 3);
    kga[c] = (size_t)(bb * SEQ + rr) * D_MODEL + hd * 64 + ss * 8;
    vga[c] = (size_t)(bh * 64 + rr) * SEQ + ss * 8;
  }
  short8v skh[2], skl[2], svh[2], svl[2];
#pragma unroll
  for (int c = 0; c < 2; c++) {
    skh[c] = *reinterpret_cast<const short8v*>(kh + kga[c]);
    skl[c] = *reinterpret_cast<const short8v*>(kl + kga[c]);
    svh[c] = *reinterpret_cast<const short8v*>(vth + vga[c]);
    svl[c] = *reinterpret_cast<const short8v*>(vtl + vga[c]);
  }

  f32x16 accO[2];
#pragma unroll
  for (int t = 0; t < 2; t++)
#pragma unroll
    for (int i = 0; i < 16; i++) accO[t][i] = 0.f;
  float mrun = -3e38f, lrun = 0.f;

  for (int kt = 0; kt < 32; kt++) {
#pragma unroll
    for (int c = 0; c < 2; c++) {
      *reinterpret_cast<short8v*>(&Kh[dst[c]]) = skh[c];
      *reinterpret_cast<short8v*>(&Kl[dst[c]]) = skl[c];
      *reinterpret_cast<short8v*>(&Vh[dst[c]]) = svh[c];
      *reinterpret_cast<short8v*>(&Vl[dst[c]]) = svl[c];
    }
    __syncthreads();
    if (kt < 31) {                       // T14: issue next tile's loads early
#pragma unroll
      for (int c = 0; c < 2; c++) {
        size_t ko = kga[c] + (size_t)(kt + 1) * 64 * D_MODEL;
        size_t vo = vga[c] + (size_t)(kt + 1) * 64;
        skh[c] = *reinterpret_cast<const short8v*>(kh + ko);
        skl[c] = *reinterpret_cast<const short8v*>(kl + ko);
        svh[c] = *reinterpret_cast<const short8v*>(vth + vo);
        svl[c] = *reinterpret_cast<const short8v*>(vtl + vo);
      }
    }

    // ---- S^T = K * Q^T (split bf16, 24 MFMAs); s in log2 units
    f32x16 sc[2];
#pragma unroll
    for (int t = 0; t < 2; t++)
#pragma unroll
      for (int i = 0; i < 16; i++) sc[t][i] = 0.f;
    __builtin_amdgcn_s_setprio(1);
#pragma unroll
    for (int t = 0; t < 2; t++) {
      const int row = 32 * t + lq;
#pragma unroll
      for (int c = 0; c < 4; c++) {
        const int idx = row * 64 + (((2 * c + hb) ^ (row & 7)) << 3);
        short8v ah = *reinterpret_cast<const short8v*>(&Kh[idx]);
        short8v al = *reinterpret_cast<const short8v*>(&Kl[idx]);
        sc[t] = __builtin_amdgcn_mfma_f32_32x32x16_bf16(ah, qfh[c], sc[t], 0, 0, 0);
        sc[t] = __builtin_amdgcn_mfma_f32_32x32x16_bf16(ah, qfl[c], sc[t], 0, 0, 0);
        sc[t] = __builtin_amdgcn_mfma_f32_32x32x16_bf16(al, qfh[c], sc[t], 0, 0, 0);
      }
    }
    __builtin_amdgcn_s_setprio(0);

    // ---- online softmax (exp2, defer-max THR=8)
    float tm = -3e38f;
#pragma unroll
    for (int t = 0; t < 2; t++)
#pragma unroll
      for (int r = 0; r < 16; r++) tm = fmaxf(tm, sc[t][r]);
    tm = fmaxf(tm, __shfl_xor(tm, 32));
    if (__any(tm - mrun > 8.f)) {
      const float mnew = fmaxf(mrun, tm);
      const float al = exp2f(mrun - mnew);
      lrun *= al;
#pragma unroll
      for (int t = 0; t < 2; t++)
#pragma unroll
        for (int i = 0; i < 16; i++) accO[t][i] *= al;
      mrun = mnew;
    }
    float p[2][16];
    float ps = 0.f;
#pragma unroll
    for (int t = 0; t < 2; t++)
#pragma unroll
      for (int r = 0; r < 16; r++) {
        p[t][r] = exp2f(sc[t][r] - mrun);
        ps += p[t][r];
      }
    ps += __shfl_xor(ps, 32);
    lrun += ps;

    // ---- pack P (single bf16) B-frags: chunk c <- p[c>>1][8*(c&1)+j]
    short8v ph[4];
#pragma unroll
    for (int c = 0; c < 4; c++)
#pragma unroll
      for (int j = 0; j < 8; j++)
        ph[c][j] = (short)f2bf(p[c >> 1][8 * (c & 1) + j]);

    // ---- O^T += V^T * P^T (16 MFMAs)
    __builtin_amdgcn_s_setprio(1);
#pragma unroll
    for (int t = 0; t < 2; t++) {
      const int row = 32 * t + lq;
#pragma unroll
      for (int c = 0; c < 4; c++) {
        const int idx = row * 64 + (((2 * c + hb) ^ (row & 7)) << 3);
        short8v vhf = *reinterpret_cast<const short8v*>(&Vh[idx]);
        short8v vlf = *reinterpret_cast<const short8v*>(&Vl[idx]);
        accO[t] = __builtin_amdgcn_mfma_f32_32x32x16_bf16(vhf, ph[c], accO[t], 0, 0, 0);
        accO[t] = __builtin_amdgcn_mfma_f32_32x32x16_bf16(vlf, ph[c], accO[t], 0, 0, 0);
      }
    }
    __builtin_amdgcn_s_setprio(0);
    __syncthreads();
  }

  // ---- epilogue: O[q][d] = O^T[d][q] / l
  const float inv = 1.f / lrun;
  const size_t obase = (size_t)(bb * SEQ + qt * 128 + wv * 32 + lq) * D_MODEL + hd * 64;
#pragma unroll
  for (int t = 0; t < 2; t++)
#pragma unroll
    for (int r = 0; r < 16; r++) {
      const int d = 32 * t + (r & 3) + ((r >> 2) << 3) + 4 * hb;
      short hh2, ll2;
      split2(accO[t][r] * inv, hh2, ll2);
      oh[obase + d] = hh2;
      ol[obase + d] = ll2;
    }
}

// ---------------------------------------------------------------- fp32 GEMM (fallback)
template<bool RELU, bool RES>
__global__ __launch_bounds__(256)
void gemm_k(const float* __restrict__ A, int K, int Ncols,
            const float* __restrict__ W0, const float* __restrict__ W1p,
            const float* __restrict__ W2p,
            const float* __restrict__ B0, const float* __restrict__ B1p,
            const float* __restrict__ B2p,
            float* __restrict__ O0, float* __restrict__ O1p, float* __restrict__ O2p,
            int nbn_per, const float* __restrict__ resid)
{
  __shared__ float As[16][132];
  __shared__ float Bs[16][132];
  const int tid = threadIdx.x;
  const int split = blockIdx.x / nbn_per;
  const int bn = (blockIdx.x % nbn_per) * 128;
  const int bm = blockIdx.y * 128;
  const float* W  = split == 0 ? W0 : (split == 1 ? W1p : W2p);
  const float* Bi = split == 0 ? B0 : (split == 1 ? B1p : B2p);
  float* O        = split == 0 ? O0 : (split == 1 ? O1p : O2p);
  const int tx = tid & 15, ty = tid >> 4;

  float4 acc[2][4][2];
#pragma unroll
  for (int a = 0; a < 2; a++)
#pragma unroll
    for (int b = 0; b < 4; b++)
#pragma unroll
      for (int c = 0; c < 2; c++) acc[a][b][c] = make_float4(0.f, 0.f, 0.f, 0.f);

  for (int k0 = 0; k0 < K; k0 += 16) {
#pragma unroll
    for (int i = 0; i < 2; i++) {
      int p = tid + i * 256;
      int row = p >> 2, kk4 = (p & 3) << 2;
      float4 va = *reinterpret_cast<const float4*>(A + (size_t)(bm + row) * K + k0 + kk4);
      As[kk4 + 0][row] = va.x; As[kk4 + 1][row] = va.y;
      As[kk4 + 2][row] = va.z; As[kk4 + 3][row] = va.w;
    }
#pragma unroll
    for (int i = 0; i < 2; i++) {
      int p = tid + i * 256;
      int row = p >> 5, c4 = (p & 31) << 2;
      *reinterpret_cast<float4*>(&Bs[row][c4]) =
          *reinterpret_cast<const float4*>(W + (size_t)(k0 + row) * Ncols + bn + c4);
    }
    __syncthreads();
#pragma unroll
    for (int kk = 0; kk < 16; kk++) {
      float4 a0 = *reinterpret_cast<const float4*>(&As[kk][ty * 4]);
      float4 a1 = *reinterpret_cast<const float4*>(&As[kk][64 + ty * 4]);
      float4 b0 = *reinterpret_cast<const float4*>(&Bs[kk][tx * 4]);
      float4 b1 = *reinterpret_cast<const float4*>(&Bs[kk][64 + tx * 4]);
      float av0[4] = {a0.x, a0.y, a0.z, a0.w};
      float av1[4] = {a1.x, a1.y, a1.z, a1.w};
#pragma unroll
      for (int j = 0; j < 4; j++) {
        FMA4(acc[0][j][0], av0[j], b0); FMA4(acc[0][j][1], av0[j], b1);
        FMA4(acc[1][j][0], av1[j], b0); FMA4(acc[1][j][1], av1[j], b1);
      }
    }
    __syncthreads();
  }

#pragma unroll
  for (int ih = 0; ih < 2; ih++)
#pragma unroll
    for (int j = 0; j < 4; j++)
#pragma unroll
      for (int jh = 0; jh < 2; jh++) {
        int row = bm + ih * 64 + ty * 4 + j;
        int col = bn + jh * 64 + tx * 4;
        float4 r = acc[ih][j][jh];
        float4 bb = *reinterpret_cast<const float4*>(Bi + col);
        r.x += bb.x; r.y += bb.y; r.z += bb.z; r.w += bb.w;
        if (RES) {
          float4 rr = *reinterpret_cast<const float4*>(resid + (size_t)row * Ncols + col);
          r.x += rr.x; r.y += rr.y; r.z += rr.z; r.w += rr.w;
        }
        if (RELU) {
          r.x = fmaxf(r.x, 0.f); r.y = fmaxf(r.y, 0.f);
          r.z = fmaxf(r.z, 0.f); r.w = fmaxf(r.w, 0.f);
        }
        *reinterpret_cast<float4*>(O + (size_t)row * Ncols + col) = r;
      }
}

// ---------------------------------------------------------------- fp32 flash attn (fallback)
__global__ __launch_bounds__(256)
void attn_k(const float* __restrict__ Q, const float* __restrict__ K,
            const float* __restrict__ V, float* __restrict__ Og)
{
  __shared__ float QsT[64][132];
  __shared__ float KsT[64][68];
  __shared__ float Vs[64][68];
  __shared__ float Ps[128][68];

  const int tid = threadIdx.x, tx = tid & 15, ty = tid >> 4;
  const int bh = blockIdx.y;
  const int bb = bh >> 4, hd = bh & 15;
  const int qt = blockIdx.x;
  const float* Qp = Q + (size_t)(bb * SEQ + qt * 128) * D_MODEL + hd * 64;
  const float* Kp = K + (size_t)(bb * SEQ) * D_MODEL + hd * 64;
  const float* Vp = V + (size_t)(bb * SEQ) * D_MODEL + hd * 64;
  const size_t obase = (size_t)(bb * SEQ + qt * 128) * D_MODEL + hd * 64;

#pragma unroll
  for (int i = 0; i < 8; i++) {
    int p = tid + i * 256;
    int r = p >> 4, k4 = (p & 15) << 2;
    float4 va = *reinterpret_cast<const float4*>(Qp + (size_t)r * D_MODEL + k4);
    QsT[k4 + 0][r] = va.x; QsT[k4 + 1][r] = va.y;
    QsT[k4 + 2][r] = va.z; QsT[k4 + 3][r] = va.w;
  }

  float4 Oa[2][4];
  float mrun[2][4], lrun[2][4];
#pragma unroll
  for (int a = 0; a < 2; a++)
#pragma unroll
    for (int j = 0; j < 4; j++) {
      Oa[a][j] = make_float4(0.f, 0.f, 0.f, 0.f);
      mrun[a][j] = -1e30f; lrun[a][j] = 0.f;
    }

  __syncthreads();

  for (int kt = 0; kt < 32; kt++) {
#pragma unroll
    for (int i = 0; i < 4; i++) {
      int p = tid + i * 256;
      int r = p >> 4, k4 = (p & 15) << 2;
      float4 kv = *reinterpret_cast<const float4*>(Kp + (size_t)(kt * 64 + r) * D_MODEL + k4);
      KsT[k4 + 0][r] = kv.x; KsT[k4 + 1][r] = kv.y;
      KsT[k4 + 2][r] = kv.z; KsT[k4 + 3][r] = kv.w;
      float4 vv = *reinterpret_cast<const float4*>(Vp + (size_t)(kt * 64 + r) * D_MODEL + k4);
      *reinterpret_cast<float4*>(&Vs[r][k4]) = vv;
    }
    __syncthreads();

    float4 sc[2][4];
#pragma unroll
    for (int a = 0; a < 2; a++)
#pragma unroll
      for (int j = 0; j < 4; j++) sc[a][j] = make_float4(0.f, 0.f, 0.f, 0.f);

#pragma unroll 8
    for (int kk = 0; kk < 64; kk++) {
      float4 b0 = *reinterpret_cast<const float4*>(&KsT[kk][tx * 4]);
      float4 a0 = *reinterpret_cast<const float4*>(&QsT[kk][ty * 4]);
      float4 a1 = *reinterpret_cast<const float4*>(&QsT[kk][64 + ty * 4]);
      float av0[4] = {a0.x, a0.y, a0.z, a0.w};
      float av1[4] = {a1.x, a1.y, a1.z, a1.w};
#pragma unroll
      for (int j = 0; j < 4; j++) {
        FMA4(sc[0][j], av0[j], b0);
        FMA4(sc[1][j], av1[j], b0);
      }
    }

#pragma unroll
    for (int a = 0; a < 2; a++)
#pragma unroll
      for (int j = 0; j < 4; j++) {
        float4 s4 = sc[a][j];
        s4.x *= 0.125f; s4.y *= 0.125f; s4.z *= 0.125f; s4.w *= 0.125f;
        float tm = fmaxf(fmaxf(s4.x, s4.y), fmaxf(s4.z, s4.w));
#pragma unroll
        for (int o = 8; o > 0; o >>= 1) tm = fmaxf(tm, __shfl_xor(tm, o));
        float mnew = fmaxf(mrun[a][j], tm);
        float alpha = __expf(mrun[a][j] - mnew);
        float4 p;
        p.x = __expf(s4.x - mnew); p.y = __expf(s4.y - mnew);
        p.z = __expf(s4.z - mnew); p.w = __expf(s4.w - mnew);
        float ps = p.x + p.y + p.z + p.w;
#pragma unroll
        for (int o = 8; o > 0; o >>= 1) ps += __shfl_xor(ps, o);
        lrun[a][j] = lrun[a][j] * alpha + ps;
        mrun[a][j] = mnew;
        Oa[a][j].x *= alpha; Oa[a][j].y *= alpha;
        Oa[a][j].z *= alpha; Oa[a][j].w *= alpha;
        *reinterpret_cast<float4*>(&Ps[a * 64 + ty * 4 + j][tx * 4]) = p;
      }
    __syncthreads();

#pragma unroll 4
    for (int k4 = 0; k4 < 16; k4++) {
      float4 b[4];
#pragma unroll
      for (int u = 0; u < 4; u++)
        b[u] = *reinterpret_cast<const float4*>(&Vs[k4 * 4 + u][tx * 4]);
#pragma unroll
      for (int a = 0; a < 2; a++)
#pragma unroll
        for (int j = 0; j < 4; j++) {
          float4 p = *reinterpret_cast<const float4*>(&Ps[a * 64 + ty * 4 + j][k4 * 4]);
          FMA4(Oa[a][j], p.x, b[0]);
          FMA4(Oa[a][j], p.y, b[1]);
          FMA4(Oa[a][j], p.z, b[2]);
          FMA4(Oa[a][j], p.w, b[3]);
        }
    }
    __syncthreads();
  }

#pragma unroll
  for (int a = 0; a < 2; a++)
#pragma unroll
    for (int j = 0; j < 4; j++) {
      float inv = 1.f / lrun[a][j];
      float4 r = Oa[a][j];
      r.x *= inv; r.y *= inv; r.z *= inv; r.w *= inv;
      *reinterpret_cast<float4*>(Og + obase + (size_t)(a * 64 + ty * 4 + j) * D_MODEL + tx * 4) = r;
    }
}

// ---------------------------------------------------------------- launch
extern "C" void kernel_launch(void* const* d_in, const int* in_sizes, int n_in,
                              void* d_out, int out_size, void* d_ws, size_t ws_size,
                              hipStream_t stream)
{
  (void)in_sizes; (void)n_in; (void)out_size;
  const float* x    = (const float*)d_in[0];
  const float* Wq   = (const float*)d_in[1];
  const float* Wk   = (const float*)d_in[2];
  const float* Wv   = (const float*)d_in[3];
  const float* Wo   = (const float*)d_in[4];
  const float* bq   = (const float*)d_in[5];
  const float* bk   = (const float*)d_in[6];
  const float* bv   = (const float*)d_in[7];
  const float* bo   = (const float*)d_in[8];
  const float* W1   = (const float*)d_in[9];
  const float* b1   = (const float*)d_in[10];
  const float* W2   = (const float*)d_in[11];
  const float* b2   = (const float*)d_in[12];
  const float* ln1w = (const float*)d_in[13];
  const float* ln1b = (const float*)d_in[14];
  const float* ln2w = (const float*)d_in[15];
  const float* ln2b = (const float*)d_in[16];
  const float* lnfw = (const float*)d_in[17];
  const float* lnfb = (const float*)d_in[18];

  const size_t ND = (size_t)NTOK * D_MODEL;     // 4M
  const size_t M1 = 1024 * 1024;
  float* xb = (float*)d_out;

  hipMemcpyAsync(xb, x, sizeof(float) * ND, hipMemcpyDeviceToDevice, stream);

  const size_t REQ_MFMA = 184549376;            // 88M shorts = 176 MB
  const bool use_mfma = (ws_size >= REQ_MFMA);

  if (use_mfma) {
    short* wT_h = (short*)d_ws;                 // 12M shorts
    short* wT_l = wT_h + 12 * M1;
    short* h_hi = wT_l + 12 * M1;
    short* h_lo = h_hi + ND;
    short* q_hi = h_lo + ND;
    short* q_lo = q_hi + ND;
    short* k_hi = q_lo + ND;
    short* k_lo = k_hi + ND;
    short* vT_h = k_lo + ND;
    short* vT_l = vT_h + ND;
    short* t_hi = vT_l + ND;
    short* t_lo = t_hi + (size_t)NTOK * FF_DIM;

    for (int i = 0; i < LLAYERS; i++) {
      WPack p;
      p.src[0] = Wq + (size_t)i * M1; p.src[1] = Wk + (size_t)i * M1;
      p.src[2] = Wv + (size_t)i * M1; p.src[3] = Wo + (size_t)i * M1;
      p.src[4] = W1 + (size_t)i * D_MODEL * FF_DIM;
      p.src[5] = W2 + (size_t)i * FF_DIM * D_MODEL;
      for (int m = 0; m < 6; m++) {
        static const size_t doff[6] = {0, M1, 2 * M1, 3 * M1, 4 * M1, 8 * M1};
        p.dhi[m] = wT_h + doff[m]; p.dlo[m] = wT_l + doff[m];
      }
      p.K[0] = p.K[1] = p.K[2] = p.K[3] = 1024; p.K[4] = 1024; p.K[5] = 4096;
      p.N[0] = p.N[1] = p.N[2] = p.N[3] = 1024; p.N[4] = 4096; p.N[5] = 1024;
      cvtw_k<<<12288, 256, 0, stream>>>(p);

      ln_k<1><<<NTOK / 4, 256, 0, stream>>>(xb, ln1w + (size_t)i * D_MODEL,
                                            ln1b + (size_t)i * D_MODEL, nullptr, h_hi, h_lo);
      // fused QKV -> q (scaled)/k hi/lo row-major, V -> phi-permuted V^T hi/lo
      mgemm_k<3><<<dim3(24, 32), 256, 0, stream>>>(
          h_hi, h_lo, 1024, 1024,
          wT_h, wT_l, wT_h + M1, wT_l + M1, wT_h + 2 * M1, wT_l + 2 * M1,
          bq + (size_t)i * D_MODEL, bk + (size_t)i * D_MODEL, bv + (size_t)i * D_MODEL,
          nullptr, nullptr, nullptr,
          q_hi, q_lo, k_hi, k_lo, vT_h, vT_l, 8, nullptr);
      mattn_k<<<dim3(16, 32), 256, 0, stream>>>(q_hi, q_lo, k_hi, k_lo, vT_h, vT_l, h_hi, h_lo);
      // x += attn @ Wo + bo
      mgemm_k<1><<<dim3(8, 32), 256, 0, stream>>>(
          h_hi, h_lo, 1024, 1024,
          wT_h + 3 * M1, wT_l + 3 * M1, wT_h + 3 * M1, wT_l + 3 * M1, wT_h + 3 * M1, wT_l + 3 * M1,
          bo + (size_t)i * D_MODEL, bo + (size_t)i * D_MODEL, bo + (size_t)i * D_MODEL,
          xb, xb, xb,
          nullptr, nullptr, nullptr, nullptr, nullptr, nullptr, 8, xb);
      ln_k<1><<<NTOK / 4, 256, 0, stream>>>(xb, ln2w + (size_t)i * D_MODEL,
                                            ln2b + (size_t)i * D_MODEL, nullptr, h_hi, h_lo);
      // t = relu(h @ W1 + b1) -> hi/lo
      mgemm_k<2><<<dim3(32, 32), 256, 0, stream>>>(
          h_hi, h_lo, 1024, 4096,
          wT_h + 4 * M1, wT_l + 4 * M1, wT_h + 4 * M1, wT_l + 4 * M1, wT_h + 4 * M1, wT_l + 4 * M1,
          b1 + (size_t)i * FF_DIM, b1 + (size_t)i * FF_DIM, b1 + (size_t)i * FF_DIM,
          nullptr, nullptr, nullptr,
          t_hi, t_lo, nullptr, nullptr, nullptr, nullptr, 32, nullptr);
      // x += t @ W2 + b2
      mgemm_k<1><<<dim3(8, 32), 256, 0, stream>>>(
          t_hi, t_lo, 4096, 1024,
          wT_h + 8 * M1, wT_l + 8 * M1, wT_h + 8 * M1, wT_l + 8 * M1, wT_h + 8 * M1, wT_l + 8 * M1,
          b2 + (size_t)i * D_MODEL, b2 + (size_t)i * D_MODEL, b2 + (size_t)i * D_MODEL,
          xb, xb, xb,
          nullptr, nullptr, nullptr, nullptr, nullptr, nullptr, 8, xb);
    }
    ln_k<0><<<NTOK / 4, 256, 0, stream>>>(xb, lnfw, lnfb, xb, nullptr, nullptr);
    return;
  }

  // ---------------- fallback: fp32 VALU path (needs 80MB ws) ----------------
  float* h  = (float*)d_ws;
  float* qb = h + ND;
  float* kb = qb + ND;
  float* vb = kb + ND;
  float* tb = qb;

  for (int i = 0; i < LLAYERS; i++) {
    const float* Wq_l = Wq + (size_t)i * M1;
    const float* Wk_l = Wk + (size_t)i * M1;
    const float* Wv_l = Wv + (size_t)i * M1;
    const float* Wo_l = Wo + (size_t)i * M1;
    const float* W1_l = W1 + (size_t)i * D_MODEL * FF_DIM;
    const float* W2_l = W2 + (size_t)i * FF_DIM * D_MODEL;

    ln_k<0><<<NTOK / 4, 256, 0, stream>>>(xb, ln1w + (size_t)i * D_MODEL,
                                          ln1b + (size_t)i * D_MODEL, h, nullptr, nullptr);
    gemm_k<false, false><<<dim3(24, 32), 256, 0, stream>>>(
        h, D_MODEL, D_MODEL, Wq_l, Wk_l, Wv_l,
        bq + (size_t)i * D_MODEL, bk + (size_t)i * D_MODEL, bv + (size_t)i * D_MODEL,
        qb, kb, vb, 8, nullptr);
    attn_k<<<dim3(16, 32), 256, 0, stream>>>(qb, kb, vb, h);
    gemm_k<false, true><<<dim3(8, 32), 256, 0, stream>>>(
        h, D_MODEL, D_MODEL, Wo_l, Wo_l, Wo_l,
        bo + (size_t)i * D_MODEL, bo + (size_t)i * D_MODEL, bo + (size_t)i * D_MODEL,
        xb, xb, xb, 8, xb);
    ln_k<0><<<NTOK / 4, 256, 0, stream>>>(xb, ln2w + (size_t)i * D_MODEL,
                                          ln2b + (size_t)i * D_MODEL, h, nullptr, nullptr);
    gemm_k<true, false><<<dim3(32, 32), 256, 0, stream>>>(
        h, D_MODEL, FF_DIM, W1_l, W1_l, W1_l,
        b1 + (size_t)i * FF_DIM, b1 + (size_t)i * FF_DIM, b1 + (size_t)i * FF_DIM,
        tb, tb, tb, 32, nullptr);
    gemm_k<false, true><<<dim3(8, 32), 256, 0, stream>>>(
        tb, FF_DIM, D_MODEL, W2_l, W2_l, W2_l,
        b2 + (size_t)i * D_MODEL, b2 + (size_t)i * D_MODEL, b2 + (size_t)i * D_MODEL,
        xb, xb, xb, 8, xb);
  }
  ln_k<0><<<NTOK / 4, 256, 0, stream>>>(xb, lnfw, lnfb, xb, nullptr, nullptr);
}